// Round 1
// baseline (1373.086 us; speedup 1.0000x reference)
//
#include <hip/hip_runtime.h>
#include <math.h>

// Problem constants
#define B_   8
#define CHI_ 256
#define CHO_ 128
#define H_   64
#define W_   64
#define HW_  4096
#define KK_  9    // 3x3

// ---------------------------------------------------------------------------
// K0: transpose w_dcn[o][c][k] -> wt[(c*9+k)*128 + o]  (for coalesced GEMM staging)
// ---------------------------------------------------------------------------
__global__ __launch_bounds__(256) void k_transpose_w(
    const float* __restrict__ w_dcn, float* __restrict__ wt) {
  int idx = blockIdx.x * 256 + threadIdx.x;  // 2304*128 = 294912
  if (idx >= CHI_ * KK_ * CHO_) return;
  int row = idx >> 7;        // c*9+k
  int o   = idx & 127;
  int c = row / 9, k = row % 9;
  wt[idx] = w_dcn[(o * CHI_ + c) * 9 + k];
}

// ---------------------------------------------------------------------------
// K1: offset conv  om[b][27][y][x] = conv3x3(x, w_off) + b_off
// block = 256 threads, grid = B*64 (one row per block)
// ---------------------------------------------------------------------------
__global__ __launch_bounds__(256) void k_offconv(
    const float* __restrict__ x, const float* __restrict__ w_off,
    const float* __restrict__ b_off, float* __restrict__ om) {
  int b = blockIdx.x >> 6;
  int y = blockIdx.x & 63;
  __shared__ float xs[32 * 3 * 66];  // [c][row][x+1] with halo
  int t = threadIdx.x;
  int xcol = t & 63, ocq = t >> 6;   // wave-uniform ocq
  int noc = (ocq < 3) ? 7 : 6;       // 27 output channels split 4 ways
  float acc[7];
#pragma unroll
  for (int j = 0; j < 7; ++j) acc[j] = 0.f;

  for (int c0 = 0; c0 < CHI_; c0 += 32) {
    __syncthreads();
    for (int idx = t; idx < 32 * 3 * 66; idx += 256) {
      int c = idx / 198, rem = idx % 198;
      int r = rem / 66, xx = rem % 66 - 1;
      int yy = y + r - 1;
      float v = 0.f;
      if (yy >= 0 && yy < H_ && xx >= 0 && xx < W_)
        v = x[((size_t)(b * CHI_ + c0 + c) * H_ + yy) * W_ + xx];
      xs[idx] = v;
    }
    __syncthreads();
    for (int c = 0; c < 32; ++c) {
      float xv[9];
#pragma unroll
      for (int ky = 0; ky < 3; ++ky)
#pragma unroll
        for (int kx = 0; kx < 3; ++kx)
          xv[ky * 3 + kx] = xs[c * 198 + ky * 66 + xcol + kx];
      for (int j = 0; j < noc; ++j) {
        int oc = ocq + 4 * j;
        const float* wp = w_off + (size_t)(oc * CHI_ + c0 + c) * 9;
#pragma unroll
        for (int k = 0; k < 9; ++k) acc[j] += xv[k] * wp[k];
      }
    }
  }
  for (int j = 0; j < noc; ++j) {
    int oc = ocq + 4 * j;
    om[((size_t)(b * 27 + oc) * H_ + y) * W_ + xcol] = acc[j] + b_off[oc];
  }
}

// ---------------------------------------------------------------------------
// K2: DCNv2 as tiled GEMM + fused BN/ReLU
// block = 256 threads, grid = B * (4096/32); tile = 32 pixels, all 128 o
// thread tile: 4 o x 4 px
// ---------------------------------------------------------------------------
__global__ __launch_bounds__(256) void k_dcn(
    const float* __restrict__ x, const float* __restrict__ wt,
    const float* __restrict__ b_dcn, const float* __restrict__ om,
    const float* __restrict__ bn_g, const float* __restrict__ bn_b,
    const float* __restrict__ bn_m, const float* __restrict__ bn_v,
    float* __restrict__ yout) {
  int b = blockIdx.x >> 7;
  int p0 = (blockIdx.x & 127) * 32;

  __shared__ int   s_iy[288], s_ix[288];          // [k][p]
  __shared__ float s_fy[288], s_fx[288], s_mk[288];
  __shared__ float sS[8 * 9 * 32];                // [cc][k][p]
  __shared__ float sW[8 * 9 * 128];               // [cc][k][o]

  int t = threadIdx.x;
  // per-(k,pixel) sampling coords from offset/mask maps
  for (int idx = t; idx < 288; idx += 256) {
    int k = idx >> 5, p = idx & 31;
    int pp = p0 + p;
    int py_i = pp >> 6, px_i = pp & 63;
    float o1 = om[(size_t)(b * 27 + k) * HW_ + pp];
    float o2 = om[(size_t)(b * 27 + 9 + k) * HW_ + pp];
    float mv = om[(size_t)(b * 27 + 18 + k) * HW_ + pp];
    float m = 1.f / (1.f + __expf(-mv));
    float py = (float)(py_i + (k / 3) - 1) + o1;
    float px = (float)(px_i + (k % 3) - 1) + o2;
    float fy = floorf(py), fx = floorf(px);
    s_iy[idx] = (int)fy;  s_ix[idx] = (int)fx;
    s_fy[idx] = py - fy;  s_fx[idx] = px - fx;
    s_mk[idx] = m;
  }

  float acc[4][4] = {{0.f}};
  int o0 = (t & 31) << 2;   // 4 output channels
  int pg = t >> 5;          // 4-pixel group (0..7)

  for (int c0 = 0; c0 < CHI_; c0 += 8) {
    __syncthreads();
    // stage sampled S (bilinear, masked)
    for (int idx = t; idx < 2304; idx += 256) {
      int cc = idx / 288, r = idx % 288;
      const float* img = x + ((size_t)(b * CHI_ + c0 + cc) << 12);
      int iy = s_iy[r], ix = s_ix[r];
      float fy = s_fy[r], fx = s_fx[r];
      bool y0ok = (iy >= 0) & (iy < H_), y1ok = (iy + 1 >= 0) & (iy + 1 < H_);
      bool x0ok = (ix >= 0) & (ix < W_), x1ok = (ix + 1 >= 0) & (ix + 1 < W_);
      float v00 = (y0ok & x0ok) ? img[iy * W_ + ix]           : 0.f;
      float v01 = (y0ok & x1ok) ? img[iy * W_ + ix + 1]       : 0.f;
      float v10 = (y1ok & x0ok) ? img[(iy + 1) * W_ + ix]     : 0.f;
      float v11 = (y1ok & x1ok) ? img[(iy + 1) * W_ + ix + 1] : 0.f;
      float v = (v00 * (1.f - fx) + v01 * fx) * (1.f - fy) +
                (v10 * (1.f - fx) + v11 * fx) * fy;
      sS[idx] = v * s_mk[r];
    }
    // stage W chunk (contiguous & coalesced thanks to K0 transpose)
    const float* wsrc = wt + (size_t)c0 * 9 * CHO_;
    for (int idx = t; idx < 9216; idx += 256) sW[idx] = wsrc[idx];
    __syncthreads();

#pragma unroll
    for (int cc = 0; cc < 8; ++cc) {
#pragma unroll
      for (int k = 0; k < 9; ++k) {
        const float4 wv = *(const float4*)&sW[(cc * 9 + k) * 128 + o0];
        const float4 sv = *(const float4*)&sS[(cc * 9 + k) * 32 + (pg << 2)];
        acc[0][0] += wv.x * sv.x; acc[0][1] += wv.x * sv.y;
        acc[0][2] += wv.x * sv.z; acc[0][3] += wv.x * sv.w;
        acc[1][0] += wv.y * sv.x; acc[1][1] += wv.y * sv.y;
        acc[1][2] += wv.y * sv.z; acc[1][3] += wv.y * sv.w;
        acc[2][0] += wv.z * sv.x; acc[2][1] += wv.z * sv.y;
        acc[2][2] += wv.z * sv.z; acc[2][3] += wv.z * sv.w;
        acc[3][0] += wv.w * sv.x; acc[3][1] += wv.w * sv.y;
        acc[3][2] += wv.w * sv.z; acc[3][3] += wv.w * sv.w;
      }
    }
  }

  // fused bias + BN + ReLU epilogue
#pragma unroll
  for (int i = 0; i < 4; ++i) {
    int o = o0 + i;
    float inv = rsqrtf(bn_v[o] + 1e-5f);
    float g = bn_g[o] * inv;
    float bias = b_dcn[o], mean = bn_m[o], beta = bn_b[o];
    float4 r;
    r.x = fmaxf((acc[i][0] + bias - mean) * g + beta, 0.f);
    r.y = fmaxf((acc[i][1] + bias - mean) * g + beta, 0.f);
    r.z = fmaxf((acc[i][2] + bias - mean) * g + beta, 0.f);
    r.w = fmaxf((acc[i][3] + bias - mean) * g + beta, 0.f);
    *(float4*)&yout[((size_t)(b * CHO_ + o) << 12) + p0 + (pg << 2)] = r;
  }
}

// ---------------------------------------------------------------------------
// K3: depthwise conv-transpose (x2 bilinear up) + 1x1 conv + sigmoid
// block = 128 threads (one per X), grid = B * 128 (one output row per block)
// ---------------------------------------------------------------------------
__global__ __launch_bounds__(128) void k_up(
    const float* __restrict__ yin, const float* __restrict__ w_up,
    const float* __restrict__ w1x1, float* __restrict__ out) {
  int b = blockIdx.x >> 7;
  int Y = blockIdx.x & 127;
  int X = threadIdx.x;

  __shared__ float sy[2 * 64 * 64];   // [row][c(64-chunk)][j]
  __shared__ float s_wup[128 * 16];
  __shared__ float s_w1[128];

  int t = threadIdx.x;
  for (int idx = t; idx < 2048; idx += 128) s_wup[idx] = w_up[idx];
  if (t < 128) s_w1[t] = w1x1[t];

  // row taps: out[Y,X] = sum_{u,v:(Y+u-2)even,(X+v-2)even} y[(Y+u-2)/2,(X+v-2)/2]*w_up[3-u,3-v]
  int i0, i1, wu0, wu1, j0, j1, wv0, wv1;
  if (Y & 1) { i0 = (Y - 1) >> 1; wu0 = 2; wu1 = 0; }
  else       { i0 = (Y - 2) / 2;  wu0 = 3; wu1 = 1; }
  i1 = i0 + 1;
  if (X & 1) { j0 = (X - 1) >> 1; wv0 = 2; wv1 = 0; }
  else       { j0 = (X - 2) / 2;  wv0 = 3; wv1 = 1; }
  j1 = j0 + 1;

  float fj0 = (j0 >= 0 && j0 < W_) ? 1.f : 0.f;
  float fj1 = (j1 >= 0 && j1 < W_) ? 1.f : 0.f;
  int j0c = max(j0, 0), j1c = min(j1, W_ - 1);
  int idx00 = wu0 * 4 + wv0, idx01 = wu0 * 4 + wv1;
  int idx10 = wu1 * 4 + wv0, idx11 = wu1 * 4 + wv1;

  float acc = 0.f;
  for (int half = 0; half < 2; ++half) {
    __syncthreads();
    for (int idx = t; idx < 8192; idx += 128) {
      int r = idx >> 12, c = (idx >> 6) & 63, j = idx & 63;
      int i = r ? i1 : i0;
      float v = 0.f;
      if (i >= 0 && i < H_)
        v = yin[(((size_t)(b * CHO_) + half * 64 + c) * H_ + i) * W_ + j];
      sy[idx] = v;
    }
    __syncthreads();
    for (int c = 0; c < 64; ++c) {
      int cg = half * 64 + c;
      float v00 = sy[c * 64 + j0c] * fj0;
      float v01 = sy[c * 64 + j1c] * fj1;
      float v10 = sy[4096 + c * 64 + j0c] * fj0;
      float v11 = sy[4096 + c * 64 + j1c] * fj1;
      float tap = s_wup[cg * 16 + idx00] * v00 + s_wup[cg * 16 + idx01] * v01 +
                  s_wup[cg * 16 + idx10] * v10 + s_wup[cg * 16 + idx11] * v11;
      acc += s_w1[cg] * tap;
    }
  }
  out[((size_t)b * 128 + Y) * 128 + X] = 1.f / (1.f + __expf(-acc));
}

// ---------------------------------------------------------------------------
extern "C" void kernel_launch(void* const* d_in, const int* in_sizes, int n_in,
                              void* d_out, int out_size, void* d_ws, size_t ws_size,
                              hipStream_t stream) {
  const float* x        = (const float*)d_in[0];
  const float* w_dcn    = (const float*)d_in[1];
  const float* b_dcn    = (const float*)d_in[2];
  const float* w_off    = (const float*)d_in[3];
  const float* b_off    = (const float*)d_in[4];
  const float* bn_gamma = (const float*)d_in[5];
  const float* bn_beta  = (const float*)d_in[6];
  const float* bn_mean  = (const float*)d_in[7];
  const float* bn_var   = (const float*)d_in[8];
  const float* w_up     = (const float*)d_in[9];
  const float* w_1x1    = (const float*)d_in[10];
  float* out = (float*)d_out;

  // workspace layout (floats): wt | om | y  -> ~21.5 MB total
  float* ws = (float*)d_ws;
  float* wt = ws;                         // 294912
  float* om = ws + 294912;                // 884736
  float* y  = ws + 294912 + 884736;       // 4194304

  k_transpose_w<<<(CHI_ * KK_ * CHO_ + 255) / 256, 256, 0, stream>>>(w_dcn, wt);
  k_offconv<<<B_ * H_, 256, 0, stream>>>(x, w_off, b_off, om);
  k_dcn<<<B_ * (HW_ / 32), 256, 0, stream>>>(x, wt, b_dcn, om,
                                             bn_gamma, bn_beta, bn_mean, bn_var, y);
  k_up<<<B_ * 128, 128, 0, stream>>>(y, w_up, w_1x1, out);
}

// Round 2
// 714.460 us; speedup vs baseline: 1.9219x; 1.9219x over previous
//
#include <hip/hip_runtime.h>
#include <math.h>

// Problem constants
#define B_   8
#define CHI_ 256
#define CHO_ 128
#define H_   64
#define W_   64
#define HW_  4096

// ---------------------------------------------------------------------------
// K0: prep — transpose weights for coalesced LDS staging
//   wt_dcn[(c*9+k)*128 + o]   (from w_dcn[o][c][k])
//   wt_off[(c*9+k)*32 + oc]   (from w_off[oc][c][k], padded 27->32 with zeros)
// ---------------------------------------------------------------------------
__global__ __launch_bounds__(256) void k_prep(
    const float* __restrict__ w_dcn, const float* __restrict__ w_off,
    float* __restrict__ wt_dcn, float* __restrict__ wt_off) {
  int idx = blockIdx.x * 256 + threadIdx.x;
  if (idx < CHI_ * 9 * CHO_) {            // 294912
    int row = idx >> 7, o = idx & 127;
    int c = row / 9, k = row - c * 9;
    wt_dcn[idx] = w_dcn[(o * CHI_ + c) * 9 + k];
  }
  if (idx < CHI_ * 9 * 32) {              // 73728
    int row = idx >> 5, oc = idx & 31;
    int c = row / 9, k = row - c * 9;
    wt_off[idx] = (oc < 27) ? w_off[(oc * CHI_ + c) * 9 + k] : 0.f;
  }
}

// ---------------------------------------------------------------------------
// K1: offset conv as tiled GEMM. Tile: 32o x 64px (one image row), K=2304.
// block=256 thr, grid=B*64. Thread tile 4o x 2px.
// ---------------------------------------------------------------------------
__global__ __launch_bounds__(256) void k_offconv(
    const float* __restrict__ x, const float* __restrict__ wt_off,
    const float* __restrict__ b_off, float* __restrict__ om) {
  int b = blockIdx.x >> 6;
  int y = blockIdx.x & 63;
  __shared__ float xs[16 * 3 * 66];   // [c][row][x+1 halo]  12.4KB
  __shared__ float sw[16 * 9 * 32];   // [c][k][o]           18.4KB
  int t = threadIdx.x;
  int og = t & 7;          // 8 o-groups of 4
  int pxg = t >> 3;        // 0..31
  int x0 = pxg * 2;

  float acc[4][2] = {{0.f}};
  for (int c0 = 0; c0 < CHI_; c0 += 16) {
    __syncthreads();
    for (int idx = t; idx < 3168; idx += 256) {
      int c = idx / 198; int rem = idx - c * 198;
      int r = rem / 66;  int xx = rem - r * 66 - 1;
      int yy = y - 1 + r;
      float v = 0.f;
      if (yy >= 0 && yy < H_ && (unsigned)xx < (unsigned)W_)
        v = x[((size_t)(b * CHI_ + c0 + c) << 12) + yy * 64 + xx];
      xs[idx] = v;
    }
    const float4* wsrc = (const float4*)(wt_off + (size_t)c0 * 9 * 32);
    float4* swd = (float4*)sw;
    for (int idx = t; idx < 1152; idx += 256) swd[idx] = wsrc[idx];
    __syncthreads();
    for (int cc = 0; cc < 16; ++cc) {
#pragma unroll
      for (int k = 0; k < 9; ++k) {
        int ky = k / 3, kx = k - 3 * ky;
        float4 wv = ((const float4*)&sw[(cc * 9 + k) * 32])[og];
        const float* xr = &xs[cc * 198 + ky * 66 + x0 + kx];
        float s0 = xr[0], s1 = xr[1];
        acc[0][0] += wv.x * s0; acc[0][1] += wv.x * s1;
        acc[1][0] += wv.y * s0; acc[1][1] += wv.y * s1;
        acc[2][0] += wv.z * s0; acc[2][1] += wv.z * s1;
        acc[3][0] += wv.w * s0; acc[3][1] += wv.w * s1;
      }
    }
  }
#pragma unroll
  for (int i = 0; i < 4; ++i) {
    int oc = og * 4 + i;
    if (oc < 27) {
      float bo = b_off[oc];
      float2 r2; r2.x = acc[i][0] + bo; r2.y = acc[i][1] + bo;
      *(float2*)&om[((size_t)(b * 27 + oc) << 12) + y * 64 + x0] = r2;
    }
  }
}

// ---------------------------------------------------------------------------
// K2: DCNv2 GEMM + fused BN/ReLU.
// Tile: 128o x 64px (one image row). block=256 thr, grid=B*64.
// Thread tile 8o x 4px. c-chunk 8. Tap addr/weight precomputed per block.
// ---------------------------------------------------------------------------
__global__ __launch_bounds__(256) void k_dcn(
    const float* __restrict__ x, const float* __restrict__ wt,
    const float* __restrict__ b_dcn, const float* __restrict__ om,
    const float* __restrict__ bn_g, const float* __restrict__ bn_b,
    const float* __restrict__ bn_m, const float* __restrict__ bn_v,
    float* __restrict__ yout) {
  int b = blockIdx.x >> 6;
  int p0 = (blockIdx.x & 63) * 64;

  __shared__ int   s_off[4][576];    // [tap][k*64+px]  9.2KB
  __shared__ float s_w[4][576];      // mask-folded tap weights  9.2KB
  __shared__ float sS[8 * 9 * 64];   // [cc][k][px]  18.4KB
  __shared__ float sW[8 * 9 * 128];  // [cc][k][o]   36.9KB

  int t = threadIdx.x;
  // phase 0: per-(k,px) sampling coords from offset/mask maps
  for (int idx = t; idx < 576; idx += 256) {
    int k = idx >> 6, p = idx & 63;
    int pp = p0 + p;
    int py_i = pp >> 6, px_i = pp & 63;
    float o1 = om[(size_t)(b * 27 + k) * HW_ + pp];
    float o2 = om[(size_t)(b * 27 + 9 + k) * HW_ + pp];
    float mv = om[(size_t)(b * 27 + 18 + k) * HW_ + pp];
    float m = 1.f / (1.f + __expf(-mv));
    float py = (float)(py_i + k / 3 - 1) + o1;
    float px = (float)(px_i + (k % 3) - 1) + o2;
    float fy = floorf(py), fx = floorf(px);
    int iy = (int)fy, ix = (int)fx;
    float wy1 = py - fy, wy0 = 1.f - wy1;
    float wx1 = px - fx, wx0 = 1.f - wx1;
    bool y0ok = (iy >= 0) & (iy < 64);
    bool y1ok = (iy >= -1) & (iy < 63);
    bool x0ok = (ix >= 0) & (ix < 64);
    bool x1ok = (ix >= -1) & (ix < 63);
    int iy0 = min(max(iy, 0), 63), iy1 = min(max(iy + 1, 0), 63);
    int ix0 = min(max(ix, 0), 63), ix1 = min(max(ix + 1, 0), 63);
    s_off[0][idx] = iy0 * 64 + ix0;  s_w[0][idx] = (y0ok && x0ok) ? m * wy0 * wx0 : 0.f;
    s_off[1][idx] = iy0 * 64 + ix1;  s_w[1][idx] = (y0ok && x1ok) ? m * wy0 * wx1 : 0.f;
    s_off[2][idx] = iy1 * 64 + ix0;  s_w[2][idx] = (y1ok && x0ok) ? m * wy1 * wx0 : 0.f;
    s_off[3][idx] = iy1 * 64 + ix1;  s_w[3][idx] = (y1ok && x1ok) ? m * wy1 * wx1 : 0.f;
  }

  float acc[8][4] = {{0.f}};
  int o0 = (t & 15) * 8;   // 8 output channels
  int pg = t >> 4;         // 16 groups of 4 px

  for (int c0 = 0; c0 < CHI_; c0 += 8) {
    __syncthreads();
    // stage sampled S
    for (int idx = t; idx < 4608; idx += 256) {
      int cc = idx / 576, r = idx - cc * 576;
      const float* img = x + ((size_t)(b * CHI_ + c0 + cc) << 12);
      float v = s_w[0][r] * img[s_off[0][r]] + s_w[1][r] * img[s_off[1][r]] +
                s_w[2][r] * img[s_off[2][r]] + s_w[3][r] * img[s_off[3][r]];
      sS[idx] = v;
    }
    // stage W chunk (coalesced float4)
    const float4* wsrc = (const float4*)(wt + (size_t)c0 * 9 * 128);
    float4* swd = (float4*)sW;
    for (int idx = t; idx < 2304; idx += 256) swd[idx] = wsrc[idx];
    __syncthreads();

#pragma unroll
    for (int cc = 0; cc < 8; ++cc) {
#pragma unroll
      for (int k = 0; k < 9; ++k) {
        int row = cc * 9 + k;
        const float4 w0 = ((const float4*)&sW[row * 128])[(o0 >> 2)];
        const float4 w1 = ((const float4*)&sW[row * 128])[(o0 >> 2) + 1];
        const float4 sv = ((const float4*)&sS[row * 64])[pg];
        float wr[8] = {w0.x, w0.y, w0.z, w0.w, w1.x, w1.y, w1.z, w1.w};
        float sr[4] = {sv.x, sv.y, sv.z, sv.w};
#pragma unroll
        for (int i = 0; i < 8; ++i)
#pragma unroll
          for (int j = 0; j < 4; ++j)
            acc[i][j] += wr[i] * sr[j];
      }
    }
  }

  int px = p0 + pg * 4;
#pragma unroll
  for (int i = 0; i < 8; ++i) {
    int o = o0 + i;
    float inv = rsqrtf(bn_v[o] + 1e-5f);
    float g = bn_g[o] * inv;
    float base = (b_dcn[o] - bn_m[o]) * g + bn_b[o];
    float4 r;
    r.x = fmaxf(acc[i][0] * g + base, 0.f);
    r.y = fmaxf(acc[i][1] * g + base, 0.f);
    r.z = fmaxf(acc[i][2] * g + base, 0.f);
    r.w = fmaxf(acc[i][3] * g + base, 0.f);
    *(float4*)&yout[((size_t)(b * CHO_ + o) << 12) + px] = r;
  }
}

// ---------------------------------------------------------------------------
// K3: depthwise conv-transpose (x2 bilinear up) + 1x1 conv + sigmoid
// block = 128 threads (one per X), grid = B * 128 (one output row per block)
// ---------------------------------------------------------------------------
__global__ __launch_bounds__(128) void k_up(
    const float* __restrict__ yin, const float* __restrict__ w_up,
    const float* __restrict__ w1x1, float* __restrict__ out) {
  int b = blockIdx.x >> 7;
  int Y = blockIdx.x & 127;
  int X = threadIdx.x;

  __shared__ float sy[2 * 64 * 64];   // [row][c(64-chunk)][j]
  __shared__ float s_wup[128 * 16];
  __shared__ float s_w1[128];

  int t = threadIdx.x;
  for (int idx = t; idx < 2048; idx += 128) s_wup[idx] = w_up[idx];
  if (t < 128) s_w1[t] = w1x1[t];

  int i0, i1, wu0, wu1, j0, j1, wv0, wv1;
  if (Y & 1) { i0 = (Y - 1) >> 1; wu0 = 2; wu1 = 0; }
  else       { i0 = (Y - 2) / 2;  wu0 = 3; wu1 = 1; }
  i1 = i0 + 1;
  if (X & 1) { j0 = (X - 1) >> 1; wv0 = 2; wv1 = 0; }
  else       { j0 = (X - 2) / 2;  wv0 = 3; wv1 = 1; }
  j1 = j0 + 1;

  float fj0 = (j0 >= 0 && j0 < W_) ? 1.f : 0.f;
  float fj1 = (j1 >= 0 && j1 < W_) ? 1.f : 0.f;
  int j0c = max(j0, 0), j1c = min(j1, W_ - 1);
  int idx00 = wu0 * 4 + wv0, idx01 = wu0 * 4 + wv1;
  int idx10 = wu1 * 4 + wv0, idx11 = wu1 * 4 + wv1;

  float acc = 0.f;
  for (int half = 0; half < 2; ++half) {
    __syncthreads();
    for (int idx = t; idx < 8192; idx += 128) {
      int r = idx >> 12, c = (idx >> 6) & 63, j = idx & 63;
      int i = r ? i1 : i0;
      float v = 0.f;
      if (i >= 0 && i < H_)
        v = yin[(((size_t)(b * CHO_) + half * 64 + c) * H_ + i) * W_ + j];
      sy[idx] = v;
    }
    __syncthreads();
    for (int c = 0; c < 64; ++c) {
      int cg = half * 64 + c;
      float v00 = sy[c * 64 + j0c] * fj0;
      float v01 = sy[c * 64 + j1c] * fj1;
      float v10 = sy[4096 + c * 64 + j0c] * fj0;
      float v11 = sy[4096 + c * 64 + j1c] * fj1;
      float tap = s_wup[cg * 16 + idx00] * v00 + s_wup[cg * 16 + idx01] * v01 +
                  s_wup[cg * 16 + idx10] * v10 + s_wup[cg * 16 + idx11] * v11;
      acc += s_w1[cg] * tap;
    }
  }
  out[((size_t)b * 128 + Y) * 128 + X] = 1.f / (1.f + __expf(-acc));
}

// ---------------------------------------------------------------------------
extern "C" void kernel_launch(void* const* d_in, const int* in_sizes, int n_in,
                              void* d_out, int out_size, void* d_ws, size_t ws_size,
                              hipStream_t stream) {
  const float* x        = (const float*)d_in[0];
  const float* w_dcn    = (const float*)d_in[1];
  const float* b_dcn    = (const float*)d_in[2];
  const float* w_off    = (const float*)d_in[3];
  const float* b_off    = (const float*)d_in[4];
  const float* bn_gamma = (const float*)d_in[5];
  const float* bn_beta  = (const float*)d_in[6];
  const float* bn_mean  = (const float*)d_in[7];
  const float* bn_var   = (const float*)d_in[8];
  const float* w_up     = (const float*)d_in[9];
  const float* w_1x1    = (const float*)d_in[10];
  float* out = (float*)d_out;

  // workspace (floats): wt_dcn | wt_off | om | y   (~21.8 MB)
  float* ws = (float*)d_ws;
  float* wt_dcn = ws;                               // 294912
  float* wt_off = ws + 294912;                      // 73728
  float* om     = ws + 294912 + 73728;              // 884736
  float* y      = ws + 294912 + 73728 + 884736;     // 4194304

  k_prep<<<1152, 256, 0, stream>>>(w_dcn, w_off, wt_dcn, wt_off);
  k_offconv<<<B_ * 64, 256, 0, stream>>>(x, wt_off, b_off, om);
  k_dcn<<<B_ * 64, 256, 0, stream>>>(x, wt_dcn, b_dcn, om,
                                     bn_gamma, bn_beta, bn_mean, bn_var, y);
  k_up<<<B_ * 128, 128, 0, stream>>>(y, w_up, w_1x1, out);
}

// Round 4
// 352.579 us; speedup vs baseline: 3.8944x; 2.0264x over previous
//
#include <hip/hip_runtime.h>
#include <math.h>

typedef __attribute__((ext_vector_type(8))) short short8;
typedef __attribute__((ext_vector_type(4))) float floatx4;

#define B_   8
#define HW_  4096

__device__ __forceinline__ unsigned short bf16r(float f) {
  union { float f; unsigned int u; } v; v.f = f;
  unsigned int u = v.u;
  return (unsigned short)((u + 0x7fffu + ((u >> 16) & 1u)) >> 16);
}

// ---------------------------------------------------------------------------
// K0: weights -> bf16, K-order = (cg of 32 channels, k inner), row-padded dims
//   wt_dcn[((cg*9+k)*128 + o)*32 + cc]
//   wt_off[((cg*9+k)*32 + oc)*32 + cc]   (27 padded to 32)
// ---------------------------------------------------------------------------
__global__ __launch_bounds__(256) void k_prep(
    const float* __restrict__ w_dcn, const float* __restrict__ w_off,
    unsigned short* __restrict__ wt_dcn, unsigned short* __restrict__ wt_off) {
  int e = blockIdx.x * 256 + threadIdx.x;
  if (e < 294912) {
    int cc = e & 31, o = (e >> 5) & 127, s = e >> 12;
    int k = s % 9, cg = s / 9, c = cg * 32 + cc;
    wt_dcn[e] = bf16r(w_dcn[(o * 256 + c) * 9 + k]);
  }
  if (e < 73728) {
    int cc = e & 31, oc = (e >> 5) & 31, s = e >> 10;
    int k = s % 9, cg = s / 9, c = cg * 32 + cc;
    wt_off[e] = (oc < 27) ? bf16r(w_off[(oc * 256 + c) * 9 + k]) : (unsigned short)0;
  }
}

// ---------------------------------------------------------------------------
// K1: offset conv via MFMA. Block tile 32o x 128px (2 rows). grid=256.
// 4 waves, wave tile 32o x 32px (2x2 16-tiles).
// ---------------------------------------------------------------------------
__global__ __launch_bounds__(256) void k_offconv(
    const float* __restrict__ x, const unsigned short* __restrict__ wt_off,
    const float* __restrict__ b_off, float* __restrict__ om) {
  int b = blockIdx.x >> 5;
  int p0 = (blockIdx.x & 31) * 128;
  __shared__ unsigned short sS[128 * 40];
  __shared__ unsigned short sW[32 * 40];
  int t = threadIdx.x;
  int px_s = t & 127, h = t >> 7;                 // staging: 16 cc per thread
  int srow = (p0 + px_s) >> 6, scol = px_s & 63;
  int lane = t & 63, wv = t >> 6;
  int l15 = lane & 15, quad = lane >> 4;
  int px0w = wv * 32;
  int aoff0 = l15 * 40 + quad * 8;
  int aoff1 = (16 + l15) * 40 + quad * 8;
  int boff0 = (px0w + l15) * 40 + quad * 8;
  int boff1 = (px0w + 16 + l15) * 40 + quad * 8;

  floatx4 acc[2][2];
#pragma unroll
  for (int i = 0; i < 2; ++i)
#pragma unroll
    for (int j = 0; j < 2; ++j) acc[i][j] = (floatx4){0.f, 0.f, 0.f, 0.f};

  for (int s = 0; s < 72; ++s) {
    int k = s % 9, cg = s / 9;
    int ky = k / 3 - 1, kx = k % 3 - 1;
    __syncthreads();
    {  // stage S (im2col) : 16 channels for this px
      int yy = srow + ky, xx = scol + kx;
      bool valid = (yy >= 0) & (yy < 64) & (xx >= 0) & (xx < 64);
      const float* p = x + (((size_t)(b * 256 + cg * 32 + h * 16)) << 12) +
                       (valid ? (yy * 64 + xx) : 0);
      unsigned int pk[8];
#pragma unroll
      for (int j = 0; j < 8; ++j) {
        float v0 = p[0]; p += 4096;
        float v1 = p[0]; p += 4096;
        if (!valid) { v0 = 0.f; v1 = 0.f; }
        pk[j] = (unsigned int)bf16r(v0) | ((unsigned int)bf16r(v1) << 16);
      }
      uint4* dst = (uint4*)&sS[px_s * 40 + h * 16];
      dst[0] = make_uint4(pk[0], pk[1], pk[2], pk[3]);
      dst[1] = make_uint4(pk[4], pk[5], pk[6], pk[7]);
    }
    if (t < 128) {  // stage W: 1024 ush
      uint4 v = ((const uint4*)(wt_off + s * 1024))[t];
      *(uint4*)&sW[(t >> 2) * 40 + (t & 3) * 8] = v;
    }
    __syncthreads();
    short8 a0 = *(const short8*)&sW[aoff0];
    short8 a1 = *(const short8*)&sW[aoff1];
    short8 b0 = *(const short8*)&sS[boff0];
    short8 b1 = *(const short8*)&sS[boff1];
    acc[0][0] = __builtin_amdgcn_mfma_f32_16x16x32_bf16(a0, b0, acc[0][0], 0, 0, 0);
    acc[0][1] = __builtin_amdgcn_mfma_f32_16x16x32_bf16(a0, b1, acc[0][1], 0, 0, 0);
    acc[1][0] = __builtin_amdgcn_mfma_f32_16x16x32_bf16(a1, b0, acc[1][0], 0, 0, 0);
    acc[1][1] = __builtin_amdgcn_mfma_f32_16x16x32_bf16(a1, b1, acc[1][1], 0, 0, 0);
  }
#pragma unroll
  for (int ot = 0; ot < 2; ++ot)
#pragma unroll
    for (int r = 0; r < 4; ++r) {
      int o = ot * 16 + quad * 4 + r;
      if (o < 27) {
        float bo = b_off[o];
#pragma unroll
        for (int pt = 0; pt < 2; ++pt) {
          int px = p0 + px0w + pt * 16 + l15;
          om[(((size_t)(b * 27 + o)) << 12) + px] = acc[ot][pt][r] + bo;
        }
      }
    }
}

// ---------------------------------------------------------------------------
// K2: DCNv2 via MFMA + fused BN/ReLU. Block = 1 row (64px) x 128o. grid=512.
// 4 waves, wave tile 64o x 32px (4x2 16-tiles). Taps precomputed in LDS.
// ---------------------------------------------------------------------------
__global__ __launch_bounds__(256) void k_dcn(
    const float* __restrict__ x, const unsigned short* __restrict__ wt,
    const float* __restrict__ b_dcn, const float* __restrict__ om,
    const float* __restrict__ bn_g, const float* __restrict__ bn_b,
    const float* __restrict__ bn_m, const float* __restrict__ bn_v,
    float* __restrict__ yout) {
  int b = blockIdx.x >> 6;
  int y = blockIdx.x & 63;
  int p0 = y * 64;
  __shared__ ushort4 s_ti[576];
  __shared__ float4 s_tw[576];
  __shared__ unsigned short sS[64 * 40];
  __shared__ unsigned short sW[128 * 40];
  int t = threadIdx.x;

  // taps: 4 clamped indices + 4 mask-folded bilinear weights per (k,px)
  for (int i = t; i < 576; i += 256) {
    int k = i >> 6, p = i & 63;
    int pp = p0 + p;
    float o1 = om[(size_t)(b * 27 + k) * HW_ + pp];
    float o2 = om[(size_t)(b * 27 + 9 + k) * HW_ + pp];
    float mv = om[(size_t)(b * 27 + 18 + k) * HW_ + pp];
    float m = 1.f / (1.f + __expf(-mv));
    float py = (float)(y + k / 3 - 1) + o1;
    float pxf = (float)(p + (k % 3) - 1) + o2;
    float fy = floorf(py), fx = floorf(pxf);
    int iy = (int)fy, ix = (int)fx;
    float wy1 = py - fy, wy0 = 1.f - wy1;
    float wx1 = pxf - fx, wx0 = 1.f - wx1;
    bool y0ok = (iy >= 0) & (iy < 64), y1ok = (iy >= -1) & (iy < 63);
    bool x0ok = (ix >= 0) & (ix < 64), x1ok = (ix >= -1) & (ix < 63);
    int iy0 = min(max(iy, 0), 63), iy1 = min(max(iy + 1, 0), 63);
    int ix0 = min(max(ix, 0), 63), ix1 = min(max(ix + 1, 0), 63);
    s_ti[i] = make_ushort4((unsigned short)(iy0 * 64 + ix0), (unsigned short)(iy0 * 64 + ix1),
                           (unsigned short)(iy1 * 64 + ix0), (unsigned short)(iy1 * 64 + ix1));
    float4 w;
    w.x = (y0ok && x0ok) ? m * wy0 * wx0 : 0.f;
    w.y = (y0ok && x1ok) ? m * wy0 * wx1 : 0.f;
    w.z = (y1ok && x0ok) ? m * wy1 * wx0 : 0.f;
    w.w = (y1ok && x1ok) ? m * wy1 * wx1 : 0.f;
    s_tw[i] = w;
  }

  int px_s = t & 63, cgrp = t >> 6;   // staging: 8 cc per thread
  int lane = t & 63, wv = t >> 6;
  int l15 = lane & 15, quad = lane >> 4;
  int o0w = (wv & 1) * 64, px0w = (wv >> 1) * 32;
  int aoff[4], boff[2];
#pragma unroll
  for (int i = 0; i < 4; ++i) aoff[i] = (o0w + i * 16 + l15) * 40 + quad * 8;
  boff[0] = (px0w + l15) * 40 + quad * 8;
  boff[1] = (px0w + 16 + l15) * 40 + quad * 8;

  floatx4 acc[4][2];
#pragma unroll
  for (int i = 0; i < 4; ++i)
#pragma unroll
    for (int j = 0; j < 2; ++j) acc[i][j] = (floatx4){0.f, 0.f, 0.f, 0.f};

  for (int s = 0; s < 72; ++s) {
    int k = s % 9, cg = s / 9;
    __syncthreads();
    {  // sample S: 8 channels for this (k, px)
      ushort4 ti = s_ti[k * 64 + px_s];
      float4 tw = s_tw[k * 64 + px_s];
      const float* img = x + (((size_t)(b * 256 + cg * 32 + cgrp * 8)) << 12);
      unsigned int pk[4];
#pragma unroll
      for (int j = 0; j < 4; ++j) {
        float v0 = tw.x * img[ti.x] + tw.y * img[ti.y] + tw.z * img[ti.z] + tw.w * img[ti.w];
        img += 4096;
        float v1 = tw.x * img[ti.x] + tw.y * img[ti.y] + tw.z * img[ti.z] + tw.w * img[ti.w];
        img += 4096;
        pk[j] = (unsigned int)bf16r(v0) | ((unsigned int)bf16r(v1) << 16);
      }
      *(uint4*)&sS[px_s * 40 + cgrp * 8] = make_uint4(pk[0], pk[1], pk[2], pk[3]);
    }
    {  // stage W: 4096 ush
      const uint4* src = (const uint4*)(wt + (size_t)s * 4096);
#pragma unroll
      for (int r = 0; r < 2; ++r) {
        int idx = t + r * 256;
        uint4 v = src[idx];
        *(uint4*)&sW[(idx >> 2) * 40 + (idx & 3) * 8] = v;
      }
    }
    __syncthreads();
    short8 af0 = *(const short8*)&sW[aoff[0]];
    short8 af1 = *(const short8*)&sW[aoff[1]];
    short8 af2 = *(const short8*)&sW[aoff[2]];
    short8 af3 = *(const short8*)&sW[aoff[3]];
    short8 bf0 = *(const short8*)&sS[boff[0]];
    short8 bf1 = *(const short8*)&sS[boff[1]];
    acc[0][0] = __builtin_amdgcn_mfma_f32_16x16x32_bf16(af0, bf0, acc[0][0], 0, 0, 0);
    acc[0][1] = __builtin_amdgcn_mfma_f32_16x16x32_bf16(af0, bf1, acc[0][1], 0, 0, 0);
    acc[1][0] = __builtin_amdgcn_mfma_f32_16x16x32_bf16(af1, bf0, acc[1][0], 0, 0, 0);
    acc[1][1] = __builtin_amdgcn_mfma_f32_16x16x32_bf16(af1, bf1, acc[1][1], 0, 0, 0);
    acc[2][0] = __builtin_amdgcn_mfma_f32_16x16x32_bf16(af2, bf0, acc[2][0], 0, 0, 0);
    acc[2][1] = __builtin_amdgcn_mfma_f32_16x16x32_bf16(af2, bf1, acc[2][1], 0, 0, 0);
    acc[3][0] = __builtin_amdgcn_mfma_f32_16x16x32_bf16(af3, bf0, acc[3][0], 0, 0, 0);
    acc[3][1] = __builtin_amdgcn_mfma_f32_16x16x32_bf16(af3, bf1, acc[3][1], 0, 0, 0);
  }

#pragma unroll
  for (int ot = 0; ot < 4; ++ot)
#pragma unroll
    for (int r = 0; r < 4; ++r) {
      int o = o0w + ot * 16 + quad * 4 + r;
      float g = bn_g[o] * rsqrtf(bn_v[o] + 1e-5f);
      float base = (b_dcn[o] - bn_m[o]) * g + bn_b[o];
#pragma unroll
      for (int pt = 0; pt < 2; ++pt) {
        int px = p0 + px0w + pt * 16 + l15;
        yout[(((size_t)(b * 128 + o)) << 12) + px] = fmaxf(acc[ot][pt][r] * g + base, 0.f);
      }
    }
}

// ---------------------------------------------------------------------------
// K3: depthwise conv-transpose (x2 bilinear up) + 1x1 conv + sigmoid
// ---------------------------------------------------------------------------
__global__ __launch_bounds__(128) void k_up(
    const float* __restrict__ yin, const float* __restrict__ w_up,
    const float* __restrict__ w1x1, float* __restrict__ out) {
  int b = blockIdx.x >> 7;
  int Y = blockIdx.x & 127;
  int X = threadIdx.x;
  __shared__ float sy[2 * 64 * 64];
  __shared__ float s_wup[128 * 16];
  __shared__ float s_w1[128];
  int t = threadIdx.x;
  for (int idx = t; idx < 2048; idx += 128) s_wup[idx] = w_up[idx];
  if (t < 128) s_w1[t] = w1x1[t];

  int i0, i1, wu0, wu1, j0, j1, wv0, wv1;
  if (Y & 1) { i0 = (Y - 1) >> 1; wu0 = 2; wu1 = 0; }
  else       { i0 = (Y - 2) / 2;  wu0 = 3; wu1 = 1; }
  i1 = i0 + 1;
  if (X & 1) { j0 = (X - 1) >> 1; wv0 = 2; wv1 = 0; }
  else       { j0 = (X - 2) / 2;  wv0 = 3; wv1 = 1; }
  j1 = j0 + 1;

  float fj0 = (j0 >= 0 && j0 < 64) ? 1.f : 0.f;
  float fj1 = (j1 >= 0 && j1 < 64) ? 1.f : 0.f;
  int j0c = max(j0, 0), j1c = min(j1, 63);
  int idx00 = wu0 * 4 + wv0, idx01 = wu0 * 4 + wv1;
  int idx10 = wu1 * 4 + wv0, idx11 = wu1 * 4 + wv1;

  float acc = 0.f;
  for (int half = 0; half < 2; ++half) {
    __syncthreads();
    for (int idx = t; idx < 8192; idx += 128) {
      int r = idx >> 12, c = (idx >> 6) & 63, j = idx & 63;
      int i = r ? i1 : i0;
      float v = 0.f;
      if (i >= 0 && i < 64)
        v = yin[(((size_t)(b * 128) + half * 64 + c) << 12) + i * 64 + j];
      sy[idx] = v;
    }
    __syncthreads();
    for (int c = 0; c < 64; ++c) {
      int cg = half * 64 + c;
      float v00 = sy[c * 64 + j0c] * fj0;
      float v01 = sy[c * 64 + j1c] * fj1;
      float v10 = sy[4096 + c * 64 + j0c] * fj0;
      float v11 = sy[4096 + c * 64 + j1c] * fj1;
      float tap = s_wup[cg * 16 + idx00] * v00 + s_wup[cg * 16 + idx01] * v01 +
                  s_wup[cg * 16 + idx10] * v10 + s_wup[cg * 16 + idx11] * v11;
      acc += s_w1[cg] * tap;
    }
  }
  out[((size_t)b * 128 + Y) * 128 + X] = 1.f / (1.f + __expf(-acc));
}

// ---------------------------------------------------------------------------
extern "C" void kernel_launch(void* const* d_in, const int* in_sizes, int n_in,
                              void* d_out, int out_size, void* d_ws, size_t ws_size,
                              hipStream_t stream) {
  const float* x        = (const float*)d_in[0];
  const float* w_dcn    = (const float*)d_in[1];
  const float* b_dcn    = (const float*)d_in[2];
  const float* w_off    = (const float*)d_in[3];
  const float* b_off    = (const float*)d_in[4];
  const float* bn_gamma = (const float*)d_in[5];
  const float* bn_beta  = (const float*)d_in[6];
  const float* bn_mean  = (const float*)d_in[7];
  const float* bn_var   = (const float*)d_in[8];
  const float* w_up     = (const float*)d_in[9];
  const float* w_1x1    = (const float*)d_in[10];
  float* out = (float*)d_out;

  // ws layout in FLOAT units (R3 bug: wt_dcn is 294912 bf16 = 147456 floats,
  // not 73728 — om/wt_off overlapped wt_dcn and float-tails decoded as bf16
  // NaN weights).  Now: wt_dcn 147456 | wt_off 36864 | om 884736 | y 4194304.
  float* ws = (float*)d_ws;
  unsigned short* wt_dcn = (unsigned short*)ws;                 // 294912 ush
  unsigned short* wt_off = (unsigned short*)(ws + 147456);      //  73728 ush
  float* om = ws + 147456 + 36864;                              // 884736 f
  float* y  = ws + 147456 + 36864 + 884736;                     // 4194304 f

  k_prep<<<1152, 256, 0, stream>>>(w_dcn, w_off, wt_dcn, wt_off);
  k_offconv<<<256, 256, 0, stream>>>(x, wt_off, b_off, om);
  k_dcn<<<512, 256, 0, stream>>>(x, wt_dcn, b_dcn, om,
                                 bn_gamma, bn_beta, bn_mean, bn_var, y);
  k_up<<<1024, 128, 0, stream>>>(y, w_up, w_1x1, out);
}

// Round 5
// 301.262 us; speedup vs baseline: 4.5578x; 1.1703x over previous
//
#include <hip/hip_runtime.h>
#include <math.h>

typedef __attribute__((ext_vector_type(8))) short short8;
typedef __attribute__((ext_vector_type(4))) float floatx4;

#define HW_ 4096

__device__ __forceinline__ unsigned short bf16r(float f) {
  union { float f; unsigned int u; } v; v.f = f;
  unsigned int u = v.u;
  return (unsigned short)((u + 0x7fffu + ((u >> 16) & 1u)) >> 16);
}
__device__ __forceinline__ float bf2f(unsigned int u) {
  union { unsigned int u; float f; } v; v.u = u << 16; return v.f;
}

// ---------------------------------------------------------------------------
// K0: weight prep (all bf16, MFMA-frag-friendly layouts) + fused tables
//   wt_dcn[((cg*9+k)*128 + o)*32 + cc]
//   wt_off[((cg*9+k)*32 + oc)*32 + cc]   (27 padded to 32)
//   vtab[o*16+t] = w1x1[o]*w_up[o][t]    (fused upsample+1x1)
//   bntab[o] = g,  bntab[128+o] = (b_dcn-mean)*g + beta
// ---------------------------------------------------------------------------
__global__ __launch_bounds__(256) void k_prep(
    const float* __restrict__ w_dcn, const float* __restrict__ w_off,
    const float* __restrict__ b_dcn,
    const float* __restrict__ bn_g, const float* __restrict__ bn_b,
    const float* __restrict__ bn_m, const float* __restrict__ bn_v,
    const float* __restrict__ w_up, const float* __restrict__ w1x1,
    unsigned short* __restrict__ wt_dcn, unsigned short* __restrict__ wt_off,
    float* __restrict__ vtab, float* __restrict__ bntab) {
  int e = blockIdx.x * 256 + threadIdx.x;
  if (e < 294912) {
    int cc = e & 31, o = (e >> 5) & 127, s = e >> 12;
    int k = s % 9, cg = s / 9, c = cg * 32 + cc;
    wt_dcn[e] = bf16r(w_dcn[(o * 256 + c) * 9 + k]);
  }
  if (e < 73728) {
    int cc = e & 31, oc = (e >> 5) & 31, s = e >> 10;
    int k = s % 9, cg = s / 9, c = cg * 32 + cc;
    wt_off[e] = (oc < 27) ? bf16r(w_off[(oc * 256 + c) * 9 + k]) : (unsigned short)0;
  }
  if (e < 2048) {
    int o = e >> 4;
    vtab[e] = w1x1[o] * w_up[e];
  }
  if (e < 128) {
    float g = bn_g[e] * rsqrtf(bn_v[e] + 1e-5f);
    bntab[e] = g;
    bntab[128 + e] = (b_dcn[e] - bn_m[e]) * g + bn_b[e];
  }
}

// ---------------------------------------------------------------------------
// K0b: x (fp32 NCHW) -> xT (bf16, [b][pixel][c]) via LDS tile transpose
// block 256, grid 1024 (b x 128 tiles of 32 px)
// ---------------------------------------------------------------------------
__global__ __launch_bounds__(256) void k_xt(
    const float* __restrict__ x, unsigned short* __restrict__ xT) {
  __shared__ unsigned short sx[32 * 264];
  int b = blockIdx.x >> 7, px0 = (blockIdx.x & 127) * 32;
  int t = threadIdx.x;
  int px = t & 31, cg = t >> 5;
  const float* xsrc = x + (((size_t)(b * 256 + cg * 32)) << 12) + px0 + px;
#pragma unroll
  for (int cc = 0; cc < 32; ++cc)
    sx[px * 264 + cg * 32 + cc] = bf16r(xsrc[(size_t)cc << 12]);
  __syncthreads();
#pragma unroll
  for (int j = 0; j < 4; ++j) {
    int unit = t + j * 256;
    int p = unit >> 5, chunk = unit & 31;
    uint4 v = *(const uint4*)&sx[p * 264 + chunk * 8];
    *(uint4*)&xT[((size_t)((b << 12) + px0 + p)) * 256 + chunk * 8] = v;
  }
}

// ---------------------------------------------------------------------------
// K1: offset conv via MFMA, ZERO LDS / ZERO barriers.
// Block 256 (4 waves), wave tile 32o x 16px; grid = 8b x 64 rows.
// A-frags direct from wt_off; B-frag = 16B load from shifted xT row.
// ---------------------------------------------------------------------------
__global__ __launch_bounds__(256) void k_offconv(
    const unsigned short* __restrict__ xT, const unsigned short* __restrict__ wt_off,
    const float* __restrict__ b_off, unsigned short* __restrict__ om) {
  int b = blockIdx.x >> 6, row = blockIdx.x & 63;
  int t = threadIdx.x, lane = t & 63, wvx = t >> 6;
  int l15 = lane & 15, quad = lane >> 4;
  int xcol = wvx * 16 + l15;
  const unsigned short* xb = xT + (((size_t)b) << 12) * 256;
  const short8 zz = {0, 0, 0, 0, 0, 0, 0, 0};

  floatx4 acc[2];
  acc[0] = (floatx4){0.f, 0.f, 0.f, 0.f};
  acc[1] = (floatx4){0.f, 0.f, 0.f, 0.f};

  for (int cg = 0; cg < 8; ++cg) {
#pragma unroll
    for (int k = 0; k < 9; ++k) {
      int s = cg * 9 + k;
      int yy = row + k / 3 - 1, xx = xcol + k % 3 - 1;
      bool valid = ((unsigned)yy < 64u) & ((unsigned)xx < 64u);
      int pix = valid ? (yy * 64 + xx) : 0;
      short8 bfrag = *(const short8*)&xb[(size_t)pix * 256 + cg * 32 + quad * 8];
      if (!valid) bfrag = zz;
      const unsigned short* wp = wt_off + (size_t)s * 1024;
      short8 a0 = *(const short8*)&wp[l15 * 32 + quad * 8];
      short8 a1 = *(const short8*)&wp[(16 + l15) * 32 + quad * 8];
      acc[0] = __builtin_amdgcn_mfma_f32_16x16x32_bf16(a0, bfrag, acc[0], 0, 0, 0);
      acc[1] = __builtin_amdgcn_mfma_f32_16x16x32_bf16(a1, bfrag, acc[1], 0, 0, 0);
    }
  }
#pragma unroll
  for (int ot = 0; ot < 2; ++ot)
#pragma unroll
    for (int r = 0; r < 4; ++r) {
      int o = ot * 16 + quad * 4 + r;
      if (o < 27)
        om[(((size_t)(b * 27 + o)) << 12) + row * 64 + xcol] = bf16r(acc[ot][r] + b_off[o]);
    }
}

// ---------------------------------------------------------------------------
// K2: DCNv2 via MFMA + fused BN/ReLU + fused (upsample x 1x1) reduction -> R.
// Block 256 (4 waves), wave tile 128o x 16px; grid = 8b x 64 rows.
// B-frag sampled in-register from xT (4 tap loads x 16B); W staged in LDS
// per k-triplet via register relay (load latency hidden under sampling VALU).
// Epilogue: R_t[px] = sum_o vtab[o][t] * relu(bn(acc)) via quad butterfly.
// ---------------------------------------------------------------------------
__global__ __launch_bounds__(256) void k_dcn(
    const unsigned short* __restrict__ xT, const unsigned short* __restrict__ wt,
    const unsigned short* __restrict__ om, const float* __restrict__ vtab,
    const float* __restrict__ bntab, float* __restrict__ R) {
  int b = blockIdx.x >> 6, row = blockIdx.x & 63;
  __shared__ unsigned short sW[3 * 128 * 32];   // 24576 B
  __shared__ ushort4 s_ti[576];
  __shared__ float4 s_tw[576];
  int t = threadIdx.x, lane = t & 63, wvx = t >> 6;
  int l15 = lane & 15, quad = lane >> 4;

  // taps: 4 clamped pixel indices + 4 mask-folded bilinear weights per (k,px)
  for (int i = t; i < 576; i += 256) {
    int k = i >> 6, p = i & 63;
    float o1 = bf2f(om[(((size_t)(b * 27 + k)) << 12) + row * 64 + p]);
    float o2 = bf2f(om[(((size_t)(b * 27 + 9 + k)) << 12) + row * 64 + p]);
    float mv = bf2f(om[(((size_t)(b * 27 + 18 + k)) << 12) + row * 64 + p]);
    float m = 1.f / (1.f + __expf(-mv));
    float py = (float)(row + k / 3 - 1) + o1;
    float pxf = (float)(p + (k % 3) - 1) + o2;
    float fy = floorf(py), fx = floorf(pxf);
    int iy = (int)fy, ix = (int)fx;
    float wy1 = py - fy, wy0 = 1.f - wy1;
    float wx1 = pxf - fx, wx0 = 1.f - wx1;
    bool y0ok = (iy >= 0) & (iy < 64), y1ok = (iy >= -1) & (iy < 63);
    bool x0ok = (ix >= 0) & (ix < 64), x1ok = (ix >= -1) & (ix < 63);
    int iy0 = min(max(iy, 0), 63), iy1 = min(max(iy + 1, 0), 63);
    int ix0 = min(max(ix, 0), 63), ix1 = min(max(ix + 1, 0), 63);
    s_ti[i] = make_ushort4((unsigned short)(iy0 * 64 + ix0), (unsigned short)(iy0 * 64 + ix1),
                           (unsigned short)(iy1 * 64 + ix0), (unsigned short)(iy1 * 64 + ix1));
    float4 w;
    w.x = (y0ok && x0ok) ? m * wy0 * wx0 : 0.f;
    w.y = (y0ok && x1ok) ? m * wy0 * wx1 : 0.f;
    w.z = (y1ok && x0ok) ? m * wy1 * wx0 : 0.f;
    w.w = (y1ok && x1ok) ? m * wy1 * wx1 : 0.f;
    s_tw[i] = w;
  }
  __syncthreads();

  int px = wvx * 16 + l15;
  const unsigned short* xb = xT + (((size_t)b) << 12) * 256;

  floatx4 acc[8];
#pragma unroll
  for (int i = 0; i < 8; ++i) acc[i] = (floatx4){0.f, 0.f, 0.f, 0.f};

  for (int phase = 0; phase < 24; ++phase) {   // phase = cg*3 + ktriplet
    // W chunk -> registers (async, overlaps sampling below)
    uint4 wreg[6];
    const uint4* wsrc = (const uint4*)(wt + (size_t)phase * 12288);
#pragma unroll
    for (int i = 0; i < 6; ++i) wreg[i] = wsrc[(wvx * 6 + i) * 64 + lane];

    // sample 3 B-frags (this wave's px, cc = cg*32 + quad*8 .. +8)
    int cbase = (phase / 3) * 32 + quad * 8;
    short8 bfr[3];
#pragma unroll
    for (int kk = 0; kk < 3; ++kk) {
      int k = (phase % 3) * 3 + kk;
      ushort4 ti = s_ti[(k << 6) + px];
      float4 tw = s_tw[(k << 6) + px];
      short8 x0 = *(const short8*)&xb[(size_t)ti.x * 256 + cbase];
      short8 x1 = *(const short8*)&xb[(size_t)ti.y * 256 + cbase];
      short8 x2 = *(const short8*)&xb[(size_t)ti.z * 256 + cbase];
      short8 x3 = *(const short8*)&xb[(size_t)ti.w * 256 + cbase];
      float r[8];
#pragma unroll
      for (int j = 0; j < 8; ++j)
        r[j] = tw.x * bf2f((unsigned short)x0[j]) + tw.y * bf2f((unsigned short)x1[j]) +
               tw.z * bf2f((unsigned short)x2[j]) + tw.w * bf2f((unsigned short)x3[j]);
      unsigned int pk0 = (unsigned int)bf16r(r[0]) | ((unsigned int)bf16r(r[1]) << 16);
      unsigned int pk1 = (unsigned int)bf16r(r[2]) | ((unsigned int)bf16r(r[3]) << 16);
      unsigned int pk2 = (unsigned int)bf16r(r[4]) | ((unsigned int)bf16r(r[5]) << 16);
      unsigned int pk3 = (unsigned int)bf16r(r[6]) | ((unsigned int)bf16r(r[7]) << 16);
      union { uint4 u; short8 s; } bu;
      bu.u = make_uint4(pk0, pk1, pk2, pk3);
      bfr[kk] = bu.s;
    }

    __syncthreads();   // previous phase's ds_reads complete (WAR on sW)
#pragma unroll
    for (int i = 0; i < 6; ++i)
      *(uint4*)&sW[((wvx * 6 + i) * 64 + lane) * 8] = wreg[i];
    __syncthreads();   // sW visible

#pragma unroll
    for (int kk = 0; kk < 3; ++kk)
#pragma unroll
      for (int ot = 0; ot < 8; ++ot) {
        short8 af = *(const short8*)&sW[(kk * 128 + ot * 16 + l15) * 32 + quad * 8];
        acc[ot] = __builtin_amdgcn_mfma_f32_16x16x32_bf16(af, bfr[kk], acc[ot], 0, 0, 0);
      }
  }

  // epilogue: BN+ReLU then R_t[px] = sum_o v[o][t]*yv, reduced over quads
  __syncthreads();
  float* sv = (float*)sW;          // 2048 vtab + 256 bn  (9216 B <= 24576)
  float* sbn = sv + 2048;
  for (int i = t; i < 2048; i += 256) sv[i] = vtab[i];
  if (t < 256) sbn[t] = bntab[t];
  __syncthreads();

  float rpart[16];
#pragma unroll
  for (int i = 0; i < 16; ++i) rpart[i] = 0.f;
#pragma unroll
  for (int ot = 0; ot < 8; ++ot)
#pragma unroll
    for (int r = 0; r < 4; ++r) {
      int o = ot * 16 + quad * 4 + r;
      float yv = fmaxf(acc[ot][r] * sbn[o] + sbn[128 + o], 0.f);
      const float* vp = &sv[o * 16];
#pragma unroll
      for (int tt = 0; tt < 16; ++tt) rpart[tt] += vp[tt] * yv;
    }
#pragma unroll
  for (int tt = 0; tt < 16; ++tt) {
    rpart[tt] += __shfl_xor(rpart[tt], 16, 64);
    rpart[tt] += __shfl_xor(rpart[tt], 32, 64);
  }
  size_t rbase = ((size_t)((b << 12) + row * 64 + px)) * 16;
#pragma unroll
  for (int j = 0; j < 4; ++j) R[rbase + quad * 4 + j] = rpart[quad * 4 + j];
}

// ---------------------------------------------------------------------------
// K3: upsample+1x1+sigmoid from R maps: 4 loads + sigmoid per output
// ---------------------------------------------------------------------------
__global__ __launch_bounds__(256) void k_upb(
    const float* __restrict__ R, float* __restrict__ out) {
  int idx = blockIdx.x * 256 + threadIdx.x;   // 131072
  int X = idx & 127, Y = (idx >> 7) & 127, b = idx >> 14;
  int i0, wu0, wu1, j0, wv0, wv1;
  if (Y & 1) { i0 = (Y - 1) >> 1; wu0 = 2; wu1 = 0; }
  else       { i0 = (Y - 2) / 2;  wu0 = 3; wu1 = 1; }
  if (X & 1) { j0 = (X - 1) >> 1; wv0 = 2; wv1 = 0; }
  else       { j0 = (X - 2) / 2;  wv0 = 3; wv1 = 1; }
  int i1 = i0 + 1, j1 = j0 + 1;
  float mi0 = ((unsigned)i0 < 64u) ? 1.f : 0.f;
  float mi1 = ((unsigned)i1 < 64u) ? 1.f : 0.f;
  float mj0 = ((unsigned)j0 < 64u) ? 1.f : 0.f;
  float mj1 = ((unsigned)j1 < 64u) ? 1.f : 0.f;
  int i0c = min(max(i0, 0), 63), i1c = min(max(i1, 0), 63);
  int j0c = min(max(j0, 0), 63), j1c = min(max(j1, 0), 63);
  const float* Rb = R + (((size_t)b) << 12) * 16;
  float s = mi0 * mj0 * Rb[(size_t)(i0c * 64 + j0c) * 16 + wu0 * 4 + wv0] +
            mi0 * mj1 * Rb[(size_t)(i0c * 64 + j1c) * 16 + wu0 * 4 + wv1] +
            mi1 * mj0 * Rb[(size_t)(i1c * 64 + j0c) * 16 + wu1 * 4 + wv0] +
            mi1 * mj1 * Rb[(size_t)(i1c * 64 + j1c) * 16 + wu1 * 4 + wv1];
  out[idx] = 1.f / (1.f + __expf(-s));
}

// ---------------------------------------------------------------------------
extern "C" void kernel_launch(void* const* d_in, const int* in_sizes, int n_in,
                              void* d_out, int out_size, void* d_ws, size_t ws_size,
                              hipStream_t stream) {
  const float* x        = (const float*)d_in[0];
  const float* w_dcn    = (const float*)d_in[1];
  const float* b_dcn    = (const float*)d_in[2];
  const float* w_off    = (const float*)d_in[3];
  const float* b_off    = (const float*)d_in[4];
  const float* bn_gamma = (const float*)d_in[5];
  const float* bn_beta  = (const float*)d_in[6];
  const float* bn_mean  = (const float*)d_in[7];
  const float* bn_var   = (const float*)d_in[8];
  const float* w_up     = (const float*)d_in[9];
  const float* w_1x1    = (const float*)d_in[10];
  float* out = (float*)d_out;

  // ws layout in FLOAT units (21.39 MB total):
  // xT 4194304 | wt_dcn 147456 | wt_off 36864 | vtab 2048 | bntab 256 |
  // om 442368 (bf16) | R 524288
  float* ws = (float*)d_ws;
  unsigned short* xT     = (unsigned short*)ws;                    // 8388608 ush
  unsigned short* wt_dcn = (unsigned short*)(ws + 4194304);        //  294912 ush
  unsigned short* wt_off = (unsigned short*)(ws + 4341760);        //   73728 ush
  float* vtab            = ws + 4378624;                           //    2048 f
  float* bntab           = ws + 4380672;                           //     256 f
  unsigned short* om     = (unsigned short*)(ws + 4380928);        //  884736 ush
  float* R               = ws + 4823296;                           //  524288 f

  k_prep<<<1152, 256, 0, stream>>>(w_dcn, w_off, b_dcn, bn_gamma, bn_beta,
                                   bn_mean, bn_var, w_up, w_1x1,
                                   wt_dcn, wt_off, vtab, bntab);
  k_xt<<<1024, 256, 0, stream>>>(x, xT);
  k_offconv<<<512, 256, 0, stream>>>(xT, wt_off, b_off, om);
  k_dcn<<<512, 256, 0, stream>>>(xT, wt_dcn, om, vtab, bntab, R);
  k_upb<<<512, 256, 0, stream>>>(R, out);
}

// Round 6
// 235.902 us; speedup vs baseline: 5.8206x; 1.2771x over previous
//
#include <hip/hip_runtime.h>
#include <math.h>

typedef __attribute__((ext_vector_type(8))) short short8;
typedef __attribute__((ext_vector_type(4))) float floatx4;

#define HW_ 4096

__device__ __forceinline__ unsigned short bf16r(float f) {
  union { float f; unsigned int u; } v; v.f = f;
  unsigned int u = v.u;
  return (unsigned short)((u + 0x7fffu + ((u >> 16) & 1u)) >> 16);
}
__device__ __forceinline__ float bf2f(unsigned int u) {
  union { unsigned int u; float f; } v; v.u = u << 16; return v.f;
}
// async global->LDS DMA, 16B per lane; LDS dst = wave-uniform base + lane*16
__device__ __forceinline__ void glds16(const void* g, void* l) {
  __builtin_amdgcn_global_load_lds(
      (const __attribute__((address_space(1))) unsigned int*)g,
      (__attribute__((address_space(3))) unsigned int*)l, 16, 0, 0);
}

// ---------------------------------------------------------------------------
// K0: weight prep (bf16, MFMA-frag layouts) + fused tables
// ---------------------------------------------------------------------------
__global__ __launch_bounds__(256) void k_prep(
    const float* __restrict__ w_dcn, const float* __restrict__ w_off,
    const float* __restrict__ b_dcn,
    const float* __restrict__ bn_g, const float* __restrict__ bn_b,
    const float* __restrict__ bn_m, const float* __restrict__ bn_v,
    const float* __restrict__ w_up, const float* __restrict__ w1x1,
    unsigned short* __restrict__ wt_dcn, unsigned short* __restrict__ wt_off,
    float* __restrict__ vtab, float* __restrict__ bntab) {
  int e = blockIdx.x * 256 + threadIdx.x;
  if (e < 294912) {
    int cc = e & 31, o = (e >> 5) & 127, s = e >> 12;
    int k = s % 9, cg = s / 9, c = cg * 32 + cc;
    wt_dcn[e] = bf16r(w_dcn[(o * 256 + c) * 9 + k]);
  }
  if (e < 73728) {
    int cc = e & 31, oc = (e >> 5) & 31, s = e >> 10;
    int k = s % 9, cg = s / 9, c = cg * 32 + cc;
    wt_off[e] = (oc < 27) ? bf16r(w_off[(oc * 256 + c) * 9 + k]) : (unsigned short)0;
  }
  if (e < 2048) {
    int o = e >> 4;
    vtab[e] = w1x1[o] * w_up[e];
  }
  if (e < 128) {
    float g = bn_g[e] * rsqrtf(bn_v[e] + 1e-5f);
    bntab[e] = g;
    bntab[128 + e] = (b_dcn[e] - bn_m[e]) * g + bn_b[e];
  }
}

// ---------------------------------------------------------------------------
// K0b: x (fp32 NCHW) -> xT (bf16, [b][pixel][c]) via LDS tile transpose
// ---------------------------------------------------------------------------
__global__ __launch_bounds__(256) void k_xt(
    const float* __restrict__ x, unsigned short* __restrict__ xT) {
  __shared__ unsigned short sx[32 * 264];
  int b = blockIdx.x >> 7, px0 = (blockIdx.x & 127) * 32;
  int t = threadIdx.x;
  int px = t & 31, cg = t >> 5;
  const float* xsrc = x + (((size_t)(b * 256 + cg * 32)) << 12) + px0 + px;
#pragma unroll
  for (int cc = 0; cc < 32; ++cc)
    sx[px * 264 + cg * 32 + cc] = bf16r(xsrc[(size_t)cc << 12]);
  __syncthreads();
#pragma unroll
  for (int j = 0; j < 4; ++j) {
    int unit = t + j * 256;
    int p = unit >> 5, chunk = unit & 31;
    uint4 v = *(const uint4*)&sx[p * 264 + chunk * 8];
    *(uint4*)&xT[((size_t)((b << 12) + px0 + p)) * 256 + chunk * 8] = v;
  }
}

// ---------------------------------------------------------------------------
// K1: offset conv via MFMA, zero LDS / zero barriers.
// ---------------------------------------------------------------------------
__global__ __launch_bounds__(256) void k_offconv(
    const unsigned short* __restrict__ xT, const unsigned short* __restrict__ wt_off,
    const float* __restrict__ b_off, unsigned short* __restrict__ om) {
  int b = blockIdx.x >> 6, row = blockIdx.x & 63;
  int t = threadIdx.x, lane = t & 63, wvx = t >> 6;
  int l15 = lane & 15, quad = lane >> 4;
  int xcol = wvx * 16 + l15;
  const unsigned short* xb = xT + (((size_t)b) << 12) * 256;
  const short8 zz = {0, 0, 0, 0, 0, 0, 0, 0};

  floatx4 acc[2];
  acc[0] = (floatx4){0.f, 0.f, 0.f, 0.f};
  acc[1] = (floatx4){0.f, 0.f, 0.f, 0.f};

  for (int cg = 0; cg < 8; ++cg) {
#pragma unroll
    for (int k = 0; k < 9; ++k) {
      int s = cg * 9 + k;
      int yy = row + k / 3 - 1, xx = xcol + k % 3 - 1;
      bool valid = ((unsigned)yy < 64u) & ((unsigned)xx < 64u);
      int pix = valid ? (yy * 64 + xx) : 0;
      short8 bfrag = *(const short8*)&xb[(size_t)pix * 256 + cg * 32 + quad * 8];
      if (!valid) bfrag = zz;
      const unsigned short* wp = wt_off + (size_t)s * 1024;
      short8 a0 = *(const short8*)&wp[l15 * 32 + quad * 8];
      short8 a1 = *(const short8*)&wp[(16 + l15) * 32 + quad * 8];
      acc[0] = __builtin_amdgcn_mfma_f32_16x16x32_bf16(a0, bfrag, acc[0], 0, 0, 0);
      acc[1] = __builtin_amdgcn_mfma_f32_16x16x32_bf16(a1, bfrag, acc[1], 0, 0, 0);
    }
  }
#pragma unroll
  for (int ot = 0; ot < 2; ++ot)
#pragma unroll
    for (int r = 0; r < 4; ++r) {
      int o = ot * 16 + quad * 4 + r;
      if (o < 27)
        om[(((size_t)(b * 27 + o)) << 12) + row * 64 + xcol] = bf16r(acc[ot][r] + b_off[o]);
    }
}

// ---------------------------------------------------------------------------
// K2: DCNv2 via MFMA + fused BN/ReLU + fused (upsample x 1x1) -> R.
// W staged via global_load_lds (no VGPR relay -> no spills, R5 bug).
// ---------------------------------------------------------------------------
__global__ __launch_bounds__(256) void k_dcn(
    const unsigned short* __restrict__ xT, const unsigned short* __restrict__ wt,
    const unsigned short* __restrict__ om, const float* __restrict__ vtab,
    const float* __restrict__ bntab, float* __restrict__ R) {
  int b = blockIdx.x >> 6, row = blockIdx.x & 63;
  __shared__ unsigned short sW[3 * 128 * 32];   // 24576 B
  __shared__ ushort4 s_ti[576];
  __shared__ float4 s_tw[576];
  int t = threadIdx.x, lane = t & 63, wvx = t >> 6;
  int l15 = lane & 15, quad = lane >> 4;

  for (int i = t; i < 576; i += 256) {
    int k = i >> 6, p = i & 63;
    float o1 = bf2f(om[(((size_t)(b * 27 + k)) << 12) + row * 64 + p]);
    float o2 = bf2f(om[(((size_t)(b * 27 + 9 + k)) << 12) + row * 64 + p]);
    float mv = bf2f(om[(((size_t)(b * 27 + 18 + k)) << 12) + row * 64 + p]);
    float m = 1.f / (1.f + __expf(-mv));
    float py = (float)(row + k / 3 - 1) + o1;
    float pxf = (float)(p + (k % 3) - 1) + o2;
    float fy = floorf(py), fx = floorf(pxf);
    int iy = (int)fy, ix = (int)fx;
    float wy1 = py - fy, wy0 = 1.f - wy1;
    float wx1 = pxf - fx, wx0 = 1.f - wx1;
    bool y0ok = (iy >= 0) & (iy < 64), y1ok = (iy >= -1) & (iy < 63);
    bool x0ok = (ix >= 0) & (ix < 64), x1ok = (ix >= -1) & (ix < 63);
    int iy0 = min(max(iy, 0), 63), iy1 = min(max(iy + 1, 0), 63);
    int ix0 = min(max(ix, 0), 63), ix1 = min(max(ix + 1, 0), 63);
    s_ti[i] = make_ushort4((unsigned short)(iy0 * 64 + ix0), (unsigned short)(iy0 * 64 + ix1),
                           (unsigned short)(iy1 * 64 + ix0), (unsigned short)(iy1 * 64 + ix1));
    float4 w;
    w.x = (y0ok && x0ok) ? m * wy0 * wx0 : 0.f;
    w.y = (y0ok && x1ok) ? m * wy0 * wx1 : 0.f;
    w.z = (y1ok && x0ok) ? m * wy1 * wx0 : 0.f;
    w.w = (y1ok && x1ok) ? m * wy1 * wx1 : 0.f;
    s_tw[i] = w;
  }
  __syncthreads();

  int px = wvx * 16 + l15;
  const unsigned short* xb = xT + (((size_t)b) << 12) * 256;

  floatx4 acc[8];
#pragma unroll
  for (int i = 0; i < 8; ++i) acc[i] = (floatx4){0.f, 0.f, 0.f, 0.f};

  for (int phase = 0; phase < 24; ++phase) {   // phase = cg*3 + ktriplet
    // W chunk -> LDS via async DMA (overlaps sampling below; __syncthreads
    // drains vmcnt so data is complete+visible before MFMA)
    {
      const unsigned short* wsrc = wt + (size_t)phase * 12288;
#pragma unroll
      for (int i = 0; i < 6; ++i) {
        int blk = wvx * 6 + i;
        glds16(wsrc + (size_t)blk * 512 + lane * 8, &sW[blk * 512]);
      }
    }

    // sample 3 B-frags (this wave's px, cc = cg*32 + quad*8 .. +8)
    int cbase = (phase / 3) * 32 + quad * 8;
    short8 bfr[3];
#pragma unroll
    for (int kk = 0; kk < 3; ++kk) {
      int k = (phase % 3) * 3 + kk;
      ushort4 ti = s_ti[(k << 6) + px];
      float4 tw = s_tw[(k << 6) + px];
      short8 x0 = *(const short8*)&xb[(size_t)ti.x * 256 + cbase];
      short8 x1 = *(const short8*)&xb[(size_t)ti.y * 256 + cbase];
      short8 x2 = *(const short8*)&xb[(size_t)ti.z * 256 + cbase];
      short8 x3 = *(const short8*)&xb[(size_t)ti.w * 256 + cbase];
      float r[8];
#pragma unroll
      for (int j = 0; j < 8; ++j)
        r[j] = tw.x * bf2f((unsigned short)x0[j]) + tw.y * bf2f((unsigned short)x1[j]) +
               tw.z * bf2f((unsigned short)x2[j]) + tw.w * bf2f((unsigned short)x3[j]);
      unsigned int pk0 = (unsigned int)bf16r(r[0]) | ((unsigned int)bf16r(r[1]) << 16);
      unsigned int pk1 = (unsigned int)bf16r(r[2]) | ((unsigned int)bf16r(r[3]) << 16);
      unsigned int pk2 = (unsigned int)bf16r(r[4]) | ((unsigned int)bf16r(r[5]) << 16);
      unsigned int pk3 = (unsigned int)bf16r(r[6]) | ((unsigned int)bf16r(r[7]) << 16);
      union { uint4 u; short8 s; } bu;
      bu.u = make_uint4(pk0, pk1, pk2, pk3);
      bfr[kk] = bu.s;
    }

    __syncthreads();   // glds complete (vmcnt drain) + visible to all waves

#pragma unroll
    for (int kk = 0; kk < 3; ++kk)
#pragma unroll
      for (int ot = 0; ot < 8; ++ot) {
        short8 af = *(const short8*)&sW[(kk * 128 + ot * 16 + l15) * 32 + quad * 8];
        acc[ot] = __builtin_amdgcn_mfma_f32_16x16x32_bf16(af, bfr[kk], acc[ot], 0, 0, 0);
      }

    __syncthreads();   // WAR: protect sW before next phase's glds
  }

  // epilogue: BN+ReLU then R_t[px] = sum_o v[o][t]*yv, reduced over quads
  float* sv = (float*)sW;          // 2048 vtab + 256 bn  (9216 B <= 24576)
  float* sbn = sv + 2048;
  for (int i = t; i < 2048; i += 256) sv[i] = vtab[i];
  if (t < 256) sbn[t] = bntab[t];
  __syncthreads();

  float rpart[16];
#pragma unroll
  for (int i = 0; i < 16; ++i) rpart[i] = 0.f;
#pragma unroll
  for (int ot = 0; ot < 8; ++ot)
#pragma unroll
    for (int r = 0; r < 4; ++r) {
      int o = ot * 16 + quad * 4 + r;
      float yv = fmaxf(acc[ot][r] * sbn[o] + sbn[128 + o], 0.f);
      const float* vp = &sv[o * 16];
#pragma unroll
      for (int tt = 0; tt < 16; ++tt) rpart[tt] += vp[tt] * yv;
    }
#pragma unroll
  for (int tt = 0; tt < 16; ++tt) {
    rpart[tt] += __shfl_xor(rpart[tt], 16, 64);
    rpart[tt] += __shfl_xor(rpart[tt], 32, 64);
  }
  size_t rbase = ((size_t)((b << 12) + row * 64 + px)) * 16;
#pragma unroll
  for (int j = 0; j < 4; ++j) R[rbase + quad * 4 + j] = rpart[quad * 4 + j];
}

// ---------------------------------------------------------------------------
// K3: upsample+1x1+sigmoid from R maps: 4 loads + sigmoid per output
// ---------------------------------------------------------------------------
__global__ __launch_bounds__(256) void k_upb(
    const float* __restrict__ R, float* __restrict__ out) {
  int idx = blockIdx.x * 256 + threadIdx.x;   // 131072
  int X = idx & 127, Y = (idx >> 7) & 127, b = idx >> 14;
  int i0, wu0, wu1, j0, wv0, wv1;
  if (Y & 1) { i0 = (Y - 1) >> 1; wu0 = 2; wu1 = 0; }
  else       { i0 = (Y - 2) / 2;  wu0 = 3; wu1 = 1; }
  if (X & 1) { j0 = (X - 1) >> 1; wv0 = 2; wv1 = 0; }
  else       { j0 = (X - 2) / 2;  wv0 = 3; wv1 = 1; }
  int i1 = i0 + 1, j1 = j0 + 1;
  float mi0 = ((unsigned)i0 < 64u) ? 1.f : 0.f;
  float mi1 = ((unsigned)i1 < 64u) ? 1.f : 0.f;
  float mj0 = ((unsigned)j0 < 64u) ? 1.f : 0.f;
  float mj1 = ((unsigned)j1 < 64u) ? 1.f : 0.f;
  int i0c = min(max(i0, 0), 63), i1c = min(max(i1, 0), 63);
  int j0c = min(max(j0, 0), 63), j1c = min(max(j1, 0), 63);
  const float* Rb = R + (((size_t)b) << 12) * 16;
  float s = mi0 * mj0 * Rb[(size_t)(i0c * 64 + j0c) * 16 + wu0 * 4 + wv0] +
            mi0 * mj1 * Rb[(size_t)(i0c * 64 + j1c) * 16 + wu0 * 4 + wv1] +
            mi1 * mj0 * Rb[(size_t)(i1c * 64 + j0c) * 16 + wu1 * 4 + wv0] +
            mi1 * mj1 * Rb[(size_t)(i1c * 64 + j1c) * 16 + wu1 * 4 + wv1];
  out[idx] = 1.f / (1.f + __expf(-s));
}

// ---------------------------------------------------------------------------
extern "C" void kernel_launch(void* const* d_in, const int* in_sizes, int n_in,
                              void* d_out, int out_size, void* d_ws, size_t ws_size,
                              hipStream_t stream) {
  const float* x        = (const float*)d_in[0];
  const float* w_dcn    = (const float*)d_in[1];
  const float* b_dcn    = (const float*)d_in[2];
  const float* w_off    = (const float*)d_in[3];
  const float* b_off    = (const float*)d_in[4];
  const float* bn_gamma = (const float*)d_in[5];
  const float* bn_beta  = (const float*)d_in[6];
  const float* bn_mean  = (const float*)d_in[7];
  const float* bn_var   = (const float*)d_in[8];
  const float* w_up     = (const float*)d_in[9];
  const float* w_1x1    = (const float*)d_in[10];
  float* out = (float*)d_out;

  // ws layout in FLOAT units (21.39 MB total):
  float* ws = (float*)d_ws;
  unsigned short* xT     = (unsigned short*)ws;                    // 8388608 ush
  unsigned short* wt_dcn = (unsigned short*)(ws + 4194304);        //  294912 ush
  unsigned short* wt_off = (unsigned short*)(ws + 4341760);        //   73728 ush
  float* vtab            = ws + 4378624;                           //    2048 f
  float* bntab           = ws + 4380672;                           //     256 f
  unsigned short* om     = (unsigned short*)(ws + 4380928);        //  884736 ush
  float* R               = ws + 4823296;                           //  524288 f

  k_prep<<<1152, 256, 0, stream>>>(w_dcn, w_off, b_dcn, bn_gamma, bn_beta,
                                   bn_mean, bn_var, w_up, w_1x1,
                                   wt_dcn, wt_off, vtab, bntab);
  k_xt<<<1024, 256, 0, stream>>>(x, xT);
  k_offconv<<<512, 256, 0, stream>>>(xT, wt_off, b_off, om);
  k_dcn<<<512, 256, 0, stream>>>(xT, wt_dcn, om, vtab, bntab, R);
  k_upb<<<512, 256, 0, stream>>>(R, out);
}

// Round 7
// 222.223 us; speedup vs baseline: 6.1789x; 1.0616x over previous
//
#include <hip/hip_runtime.h>
#include <math.h>

typedef __attribute__((ext_vector_type(8))) short short8;
typedef __attribute__((ext_vector_type(4))) float floatx4;

__device__ __forceinline__ unsigned short bf16r(float f) {
  union { float f; unsigned int u; } v; v.f = f;
  unsigned int u = v.u;
  return (unsigned short)((u + 0x7fffu + ((u >> 16) & 1u)) >> 16);
}
// round-half-up pack (sampling path; 2 ops)
__device__ __forceinline__ unsigned int bf16h(float f) {
  union { float f; unsigned int u; } v; v.f = f;
  return (v.u + 0x8000u) >> 16;
}
__device__ __forceinline__ float bf2f(unsigned int u) {
  union { unsigned int u; float f; } v; v.u = u << 16; return v.f;
}
// async global->LDS DMA, 16B/lane; LDS dst = wave-uniform base + lane*16
__device__ __forceinline__ void glds16(const void* g, void* l) {
  __builtin_amdgcn_global_load_lds(
      (const __attribute__((address_space(1))) unsigned int*)g,
      (__attribute__((address_space(3))) unsigned int*)l, 16, 0, 0);
}

// ---------------------------------------------------------------------------
// K0: weight prep (bf16, MFMA-frag layouts) + fused tables
// ---------------------------------------------------------------------------
__global__ __launch_bounds__(256) void k_prep(
    const float* __restrict__ w_dcn, const float* __restrict__ w_off,
    const float* __restrict__ b_dcn,
    const float* __restrict__ bn_g, const float* __restrict__ bn_b,
    const float* __restrict__ bn_m, const float* __restrict__ bn_v,
    const float* __restrict__ w_up, const float* __restrict__ w1x1,
    unsigned short* __restrict__ wt_dcn, unsigned short* __restrict__ wt_off,
    float* __restrict__ vtab, float* __restrict__ bntab) {
  int e = blockIdx.x * 256 + threadIdx.x;
  if (e < 294912) {
    int cc = e & 31, o = (e >> 5) & 127, s = e >> 12;
    int k = s % 9, cg = s / 9, c = cg * 32 + cc;
    wt_dcn[e] = bf16r(w_dcn[(o * 256 + c) * 9 + k]);
  }
  if (e < 73728) {
    int cc = e & 31, oc = (e >> 5) & 31, s = e >> 10;
    int k = s % 9, cg = s / 9, c = cg * 32 + cc;
    wt_off[e] = (oc < 27) ? bf16r(w_off[(oc * 256 + c) * 9 + k]) : (unsigned short)0;
  }
  if (e < 2048) {
    int o = e >> 4;
    vtab[e] = w1x1[o] * w_up[e];
  }
  if (e < 128) {
    float g = bn_g[e] * rsqrtf(bn_v[e] + 1e-5f);
    bntab[e] = g;
    bntab[128 + e] = (b_dcn[e] - bn_m[e]) * g + bn_b[e];
  }
}

// ---------------------------------------------------------------------------
// K0b: x (fp32 NCHW) -> xT (bf16, [b][pixel][c]) via LDS tile transpose
// ---------------------------------------------------------------------------
__global__ __launch_bounds__(256) void k_xt(
    const float* __restrict__ x, unsigned short* __restrict__ xT) {
  __shared__ unsigned short sx[32 * 264];
  int b = blockIdx.x >> 7, px0 = (blockIdx.x & 127) * 32;
  int t = threadIdx.x;
  int px = t & 31, cg = t >> 5;
  const float* xsrc = x + (((size_t)(b * 256 + cg * 32)) << 12) + px0 + px;
#pragma unroll
  for (int cc = 0; cc < 32; ++cc)
    sx[px * 264 + cg * 32 + cc] = bf16r(xsrc[(size_t)cc << 12]);
  __syncthreads();
#pragma unroll
  for (int j = 0; j < 4; ++j) {
    int unit = t + j * 256;
    int p = unit >> 5, chunk = unit & 31;
    uint4 v = *(const uint4*)&sx[p * 264 + chunk * 8];
    *(uint4*)&xT[((size_t)((b << 12) + px0 + p)) * 256 + chunk * 8] = v;
  }
}

// ---------------------------------------------------------------------------
// K1: offset conv via MFMA, zero LDS / zero barriers, batched loads (MLP).
// ---------------------------------------------------------------------------
__global__ __launch_bounds__(256, 2) void k_offconv(
    const unsigned short* __restrict__ xT, const unsigned short* __restrict__ wt_off,
    const float* __restrict__ b_off, unsigned short* __restrict__ om) {
  int b = blockIdx.x >> 6, row = blockIdx.x & 63;
  int t = threadIdx.x, lane = t & 63, wvx = t >> 6;
  int l15 = lane & 15, quad = lane >> 4;
  int xcol = wvx * 16 + l15;
  const unsigned short* xb = xT + (((size_t)b) << 12) * 256;
  const short8 zz = {0, 0, 0, 0, 0, 0, 0, 0};

  // hoist per-k pixel index + validity (same for every cg)
  int pixk[9]; bool vk[9];
#pragma unroll
  for (int k = 0; k < 9; ++k) {
    int yy = row + k / 3 - 1, xx = xcol + k % 3 - 1;
    vk[k] = ((unsigned)yy < 64u) & ((unsigned)xx < 64u);
    pixk[k] = vk[k] ? (yy * 64 + xx) : 0;
  }

  floatx4 acc[2];
  acc[0] = (floatx4){0.f, 0.f, 0.f, 0.f};
  acc[1] = (floatx4){0.f, 0.f, 0.f, 0.f};

  for (int cg = 0; cg < 8; ++cg) {
    int cb = cg * 32 + quad * 8;
    short8 bx[9];
#pragma unroll
    for (int k = 0; k < 9; ++k) {             // 9 independent loads in flight
      short8 v = *(const short8*)&xb[(size_t)pixk[k] * 256 + cb];
      bx[k] = vk[k] ? v : zz;
    }
#pragma unroll
    for (int k = 0; k < 9; ++k) {
      const unsigned short* wp = wt_off + (size_t)(cg * 9 + k) * 1024;
      short8 a0 = *(const short8*)&wp[l15 * 32 + quad * 8];
      short8 a1 = *(const short8*)&wp[(16 + l15) * 32 + quad * 8];
      acc[0] = __builtin_amdgcn_mfma_f32_16x16x32_bf16(a0, bx[k], acc[0], 0, 0, 0);
      acc[1] = __builtin_amdgcn_mfma_f32_16x16x32_bf16(a1, bx[k], acc[1], 0, 0, 0);
    }
  }
#pragma unroll
  for (int ot = 0; ot < 2; ++ot)
#pragma unroll
    for (int r = 0; r < 4; ++r) {
      int o = ot * 16 + quad * 4 + r;
      if (o < 27)
        om[(((size_t)(b * 27 + o)) << 12) + row * 64 + xcol] = bf16r(acc[ot][r] + b_off[o]);
    }
}

// ---------------------------------------------------------------------------
// K2: DCNv2 via MFMA + fused BN/ReLU + fused (upsample x 1x1) -> R.
// Double-buffered W (glds) + tap prefetch one phase ahead; ONE barrier/phase.
// ---------------------------------------------------------------------------
__global__ __launch_bounds__(256, 2) void k_dcn(
    const unsigned short* __restrict__ xT, const unsigned short* __restrict__ wt,
    const unsigned short* __restrict__ om, const float* __restrict__ vtab,
    const float* __restrict__ bntab, float* __restrict__ R) {
  int b = blockIdx.x >> 6, row = blockIdx.x & 63;
  __shared__ unsigned short sW[2 * 12288];   // 2 x 24576 B
  __shared__ ushort4 s_ti[576];
  __shared__ float4 s_tw[576];
  int t = threadIdx.x, lane = t & 63, wvx = t >> 6;
  int l15 = lane & 15, quad = lane >> 4;

  // prologue: taps = 4 clamped pixel indices + 4 mask-folded weights per (k,px)
  for (int i = t; i < 576; i += 256) {
    int k = i >> 6, p = i & 63;
    float o1 = bf2f(om[(((size_t)(b * 27 + k)) << 12) + row * 64 + p]);
    float o2 = bf2f(om[(((size_t)(b * 27 + 9 + k)) << 12) + row * 64 + p]);
    float mv = bf2f(om[(((size_t)(b * 27 + 18 + k)) << 12) + row * 64 + p]);
    float m = 1.f / (1.f + __expf(-mv));
    float py = (float)(row + k / 3 - 1) + o1;
    float pxf = (float)(p + (k % 3) - 1) + o2;
    float fy = floorf(py), fx = floorf(pxf);
    int iy = (int)fy, ix = (int)fx;
    float wy1 = py - fy, wy0 = 1.f - wy1;
    float wx1 = pxf - fx, wx0 = 1.f - wx1;
    bool y0ok = (iy >= 0) & (iy < 64), y1ok = (iy >= -1) & (iy < 63);
    bool x0ok = (ix >= 0) & (ix < 64), x1ok = (ix >= -1) & (ix < 63);
    int iy0 = min(max(iy, 0), 63), iy1 = min(max(iy + 1, 0), 63);
    int ix0 = min(max(ix, 0), 63), ix1 = min(max(ix + 1, 0), 63);
    s_ti[i] = make_ushort4((unsigned short)(iy0 * 64 + ix0), (unsigned short)(iy0 * 64 + ix1),
                           (unsigned short)(iy1 * 64 + ix0), (unsigned short)(iy1 * 64 + ix1));
    float4 w;
    w.x = (y0ok && x0ok) ? m * wy0 * wx0 : 0.f;
    w.y = (y0ok && x1ok) ? m * wy0 * wx1 : 0.f;
    w.z = (y1ok && x0ok) ? m * wy1 * wx0 : 0.f;
    w.w = (y1ok && x1ok) ? m * wy1 * wx1 : 0.f;
    s_tw[i] = w;
  }
  __syncthreads();   // s_ti/s_tw ready (read-only hereafter)

  int px = wvx * 16 + l15;
  const unsigned short* xb = xT + (((size_t)b) << 12) * 256;

  floatx4 acc[8];
#pragma unroll
  for (int i = 0; i < 8; ++i) acc[i] = (floatx4){0.f, 0.f, 0.f, 0.f};

  // tap raw data for current phase (prefetched one phase ahead)
  uint4 traw[12];   // [kk][tap]
  {
    int cbase = quad * 8;                       // phase 0: cg=0
#pragma unroll
    for (int kk = 0; kk < 3; ++kk) {
      ushort4 ti = s_ti[(kk << 6) + px];        // phase 0: k = kk
      traw[kk * 4 + 0] = *(const uint4*)&xb[(size_t)ti.x * 256 + cbase];
      traw[kk * 4 + 1] = *(const uint4*)&xb[(size_t)ti.y * 256 + cbase];
      traw[kk * 4 + 2] = *(const uint4*)&xb[(size_t)ti.z * 256 + cbase];
      traw[kk * 4 + 3] = *(const uint4*)&xb[(size_t)ti.w * 256 + cbase];
    }
  }
  {  // glds W(phase 0) -> buf 0
    const unsigned short* wsrc = wt;
#pragma unroll
    for (int i = 0; i < 6; ++i) {
      int blk = wvx * 6 + i;
      glds16(wsrc + (size_t)blk * 512 + lane * 8, &sW[blk * 512]);
    }
  }
  __syncthreads();   // buf0 complete (vmcnt drain) + taps in regs

  for (int phase = 0; phase < 24; ++phase) {
    unsigned short* buf = sW + (phase & 1) * 12288;
    unsigned short* nbuf = sW + ((phase + 1) & 1) * 12288;
    // issue next W DMA first (overlaps everything below)
    if (phase < 23) {
      const unsigned short* wsrc = wt + (size_t)(phase + 1) * 12288;
#pragma unroll
      for (int i = 0; i < 6; ++i) {
        int blk = wvx * 6 + i;
        glds16(wsrc + (size_t)blk * 512 + lane * 8, &nbuf[blk * 512]);
      }
    }
    int nphase = phase + 1;
    int ncbase = (nphase / 3) * 32 + quad * 8;

#pragma unroll
    for (int kk = 0; kk < 3; ++kk) {
      int k = (phase % 3) * 3 + kk;
      // compute bfr from prefetched taps
      float4 tw = s_tw[(k << 6) + px];
      union { uint4 u; short8 s; } x0, x1, x2, x3;
      x0.u = traw[kk * 4 + 0]; x1.u = traw[kk * 4 + 1];
      x2.u = traw[kk * 4 + 2]; x3.u = traw[kk * 4 + 3];
      // prefetch taps for next phase into same slots (consumed above)
      if (phase < 23) {
        int nk = (nphase % 3) * 3 + kk;
        ushort4 ti = s_ti[(nk << 6) + px];
        traw[kk * 4 + 0] = *(const uint4*)&xb[(size_t)ti.x * 256 + ncbase];
        traw[kk * 4 + 1] = *(const uint4*)&xb[(size_t)ti.y * 256 + ncbase];
        traw[kk * 4 + 2] = *(const uint4*)&xb[(size_t)ti.z * 256 + ncbase];
        traw[kk * 4 + 3] = *(const uint4*)&xb[(size_t)ti.w * 256 + ncbase];
      }
      float r[8];
#pragma unroll
      for (int j = 0; j < 8; ++j)
        r[j] = tw.x * bf2f((unsigned short)x0.s[j]) + tw.y * bf2f((unsigned short)x1.s[j]) +
               tw.z * bf2f((unsigned short)x2.s[j]) + tw.w * bf2f((unsigned short)x3.s[j]);
      union { uint4 u; short8 s; } bu;
      bu.u = make_uint4(bf16h(r[0]) | (bf16h(r[1]) << 16), bf16h(r[2]) | (bf16h(r[3]) << 16),
                        bf16h(r[4]) | (bf16h(r[5]) << 16), bf16h(r[6]) | (bf16h(r[7]) << 16));
      // MFMA for this kk (buf was completed by previous phase's barrier)
#pragma unroll
      for (int ot = 0; ot < 8; ++ot) {
        short8 af = *(const short8*)&buf[(kk * 128 + ot * 16 + l15) * 32 + quad * 8];
        acc[ot] = __builtin_amdgcn_mfma_f32_16x16x32_bf16(af, bu.s, acc[ot], 0, 0, 0);
      }
    }
    __syncthreads();  // drains glds(next) + all waves done reading buf
  }

  // epilogue: BN+ReLU then R_t[px] = sum_o v[o][t]*yv, reduced over quads
  float* sv = (float*)sW;          // 2048 vtab + 256 bn (9216 B <= 49152)
  float* sbn = sv + 2048;
  for (int i = t; i < 2048; i += 256) sv[i] = vtab[i];
  if (t < 256) sbn[t] = bntab[t];
  __syncthreads();

  float rpart[16];
#pragma unroll
  for (int i = 0; i < 16; ++i) rpart[i] = 0.f;
#pragma unroll
  for (int ot = 0; ot < 8; ++ot)
#pragma unroll
    for (int r = 0; r < 4; ++r) {
      int o = ot * 16 + quad * 4 + r;
      float yv = fmaxf(acc[ot][r] * sbn[o] + sbn[128 + o], 0.f);
      const float* vp = &sv[o * 16];
#pragma unroll
      for (int tt = 0; tt < 16; ++tt) rpart[tt] += vp[tt] * yv;
    }
#pragma unroll
  for (int tt = 0; tt < 16; ++tt) {
    rpart[tt] += __shfl_xor(rpart[tt], 16, 64);
    rpart[tt] += __shfl_xor(rpart[tt], 32, 64);
  }
  size_t rbase = ((size_t)((b << 12) + row * 64 + px)) * 16;
#pragma unroll
  for (int j = 0; j < 4; ++j) R[rbase + quad * 4 + j] = rpart[quad * 4 + j];
}

// ---------------------------------------------------------------------------
// K3: upsample+1x1+sigmoid from R maps: 4 loads + sigmoid per output
// ---------------------------------------------------------------------------
__global__ __launch_bounds__(256) void k_upb(
    const float* __restrict__ R, float* __restrict__ out) {
  int idx = blockIdx.x * 256 + threadIdx.x;   // 131072
  int X = idx & 127, Y = (idx >> 7) & 127, b = idx >> 14;
  int i0, wu0, wu1, j0, wv0, wv1;
  if (Y & 1) { i0 = (Y - 1) >> 1; wu0 = 2; wu1 = 0; }
  else       { i0 = (Y - 2) / 2;  wu0 = 3; wu1 = 1; }
  if (X & 1) { j0 = (X - 1) >> 1; wv0 = 2; wv1 = 0; }
  else       { j0 = (X - 2) / 2;  wv0 = 3; wv1 = 1; }
  int i1 = i0 + 1, j1 = j0 + 1;
  float mi0 = ((unsigned)i0 < 64u) ? 1.f : 0.f;
  float mi1 = ((unsigned)i1 < 64u) ? 1.f : 0.f;
  float mj0 = ((unsigned)j0 < 64u) ? 1.f : 0.f;
  float mj1 = ((unsigned)j1 < 64u) ? 1.f : 0.f;
  int i0c = min(max(i0, 0), 63), i1c = min(max(i1, 0), 63);
  int j0c = min(max(j0, 0), 63), j1c = min(max(j1, 0), 63);
  const float* Rb = R + (((size_t)b) << 12) * 16;
  float s = mi0 * mj0 * Rb[(size_t)(i0c * 64 + j0c) * 16 + wu0 * 4 + wv0] +
            mi0 * mj1 * Rb[(size_t)(i0c * 64 + j1c) * 16 + wu0 * 4 + wv1] +
            mi1 * mj0 * Rb[(size_t)(i1c * 64 + j0c) * 16 + wu1 * 4 + wv0] +
            mi1 * mj1 * Rb[(size_t)(i1c * 64 + j1c) * 16 + wu1 * 4 + wv1];
  out[idx] = 1.f / (1.f + __expf(-s));
}

// ---------------------------------------------------------------------------
extern "C" void kernel_launch(void* const* d_in, const int* in_sizes, int n_in,
                              void* d_out, int out_size, void* d_ws, size_t ws_size,
                              hipStream_t stream) {
  const float* x        = (const float*)d_in[0];
  const float* w_dcn    = (const float*)d_in[1];
  const float* b_dcn    = (const float*)d_in[2];
  const float* w_off    = (const float*)d_in[3];
  const float* b_off    = (const float*)d_in[4];
  const float* bn_gamma = (const float*)d_in[5];
  const float* bn_beta  = (const float*)d_in[6];
  const float* bn_mean  = (const float*)d_in[7];
  const float* bn_var   = (const float*)d_in[8];
  const float* w_up     = (const float*)d_in[9];
  const float* w_1x1    = (const float*)d_in[10];
  float* out = (float*)d_out;

  // ws layout in FLOAT units (21.39 MB total):
  float* ws = (float*)d_ws;
  unsigned short* xT     = (unsigned short*)ws;                    // 8388608 ush
  unsigned short* wt_dcn = (unsigned short*)(ws + 4194304);        //  294912 ush
  unsigned short* wt_off = (unsigned short*)(ws + 4341760);        //   73728 ush
  float* vtab            = ws + 4378624;                           //    2048 f
  float* bntab           = ws + 4380672;                           //     256 f
  unsigned short* om     = (unsigned short*)(ws + 4380928);        //  884736 ush
  float* R               = ws + 4823296;                           //  524288 f

  k_prep<<<1152, 256, 0, stream>>>(w_dcn, w_off, b_dcn, bn_gamma, bn_beta,
                                   bn_mean, bn_var, w_up, w_1x1,
                                   wt_dcn, wt_off, vtab, bntab);
  k_xt<<<1024, 256, 0, stream>>>(x, xT);
  k_offconv<<<512, 256, 0, stream>>>(xT, wt_off, b_off, om);
  k_dcn<<<512, 256, 0, stream>>>(xT, wt_dcn, om, vtab, bntab, R);
  k_upb<<<512, 256, 0, stream>>>(R, out);
}